// Round 10
// baseline (452.630 us; speedup 1.0000x reference)
//
#include <hip/hip_runtime.h>
#include <hip/hip_bf16.h>
#include <stdint.h>

#define N_GRAPH 8
#define V_NODES 4608
#define E_PER   73728
#define NV      (N_GRAPH * V_NODES)   // 36864
#define E_TOT   (N_GRAPH * E_PER)     // 589824
#define C       512
#define NCLS    3
#define LN_EPS  1e-5f
#define POOL_CHUNKS 36                // V_NODES / 128
#define SCAN_BLOCKS 144               // NV / 256
#define DPB     576                   // targets per deg/fill block (V_NODES/8)

typedef __attribute__((ext_vector_type(8))) short short8;
typedef __attribute__((ext_vector_type(4))) float floatx4;
typedef __attribute__((address_space(1))) void v_g;
typedef __attribute__((address_space(3))) void v_l;

// ---------------- helpers ----------------

__device__ inline float waveReduceSum(float v) {
#pragma unroll
    for (int o = 32; o > 0; o >>= 1) v += __shfl_down(v, o, 64);
    return v; // valid on lane 0
}

__device__ inline float waveAllSum(float v) {   // butterfly: all lanes get total
#pragma unroll
    for (int o = 32; o > 0; o >>= 1) v += __shfl_xor(v, o, 64);
    return v;
}

__device__ inline float blockSum512(float v, volatile float* sred) {
    float s = waveReduceSum(v);
    if ((threadIdx.x & 63) == 0) sred[threadIdx.x >> 6] = s;
    __syncthreads();
    float t = 0.f;
#pragma unroll
    for (int i = 0; i < 8; i++) t += sred[i];
    __syncthreads();
    return t;
}

__device__ inline unsigned short f2bf(float f) {   // RNE
    uint32_t u = __float_as_uint(f);
    u += 0x7fffu + ((u >> 16) & 1u);
    return (unsigned short)(u >> 16);
}
__device__ inline float bf2f(unsigned short b) {
    return __uint_as_float(((uint32_t)b) << 16);
}

// -------- graph preprocessing: LDS-accumulated, zero global atomics --------
// 64 blocks = 8 per graph; block owns DPB=576 targets of its graph. Scans all
// of the graph's edge targets (coalesced, L2-fit) and accumulates deg/count
// for owned targets in LDS (CU-local ds_add), then writes dinv/counts direct.

__launch_bounds__(1024)
__global__ void k_deg_lds(const int* __restrict__ ei, const float* __restrict__ ew,
                          float* __restrict__ dinv, int* __restrict__ counts) {
    __shared__ float degl[DPB];
    __shared__ int   cntl[DPB];
    const int b = blockIdx.x;
    const int g = b >> 3, part = b & 7;
    const int t0 = part * DPB;               // local target base within graph
    const int tid = threadIdx.x;
    for (int i = tid; i < DPB; i += 1024) { degl[i] = 1.0f; cntl[i] = 0; } // self-loop w=1
    __syncthreads();
    const int*   tgt = ei + E_TOT + g * E_PER;
    const float* w   = ew + g * E_PER;
    for (int e = tid; e < E_PER; e += 1024) {
        int tl = tgt[e] - t0;
        if ((unsigned)tl < DPB) {
            atomicAdd(&degl[tl], w[e]);
            atomicAdd(&cntl[tl], 1);
        }
    }
    __syncthreads();
    for (int i = tid; i < DPB; i += 1024) {
        int node = g * V_NODES + t0 + i;
        dinv[node]   = rsqrtf(degl[i]);      // deg >= 1.0 (self-loop)
        counts[node] = cntl[i];
    }
}

// ---- multi-block exclusive scan of counts -> row_ptr (3 small kernels) ----

__global__ void k_scan1(const int* __restrict__ counts, int* __restrict__ row_ptr,
                        int* __restrict__ bsum) {
    __shared__ int sh[256];
    const int b = blockIdx.x, tid = threadIdx.x;
    const int idx = b * 256 + tid;
    int v = counts[idx];
    sh[tid] = v;
    __syncthreads();
#pragma unroll
    for (int off = 1; off < 256; off <<= 1) {
        int t = (tid >= off) ? sh[tid - off] : 0;
        __syncthreads();
        sh[tid] += t;
        __syncthreads();
    }
    row_ptr[idx] = sh[tid] - v;            // exclusive within block
    if (tid == 255) bsum[b] = sh[255];     // block total
}

__global__ void k_scan2(int* __restrict__ bsum) {   // 1 block, 256 threads
    __shared__ int sh[256];
    const int tid = threadIdx.x;
    int v = (tid < SCAN_BLOCKS) ? bsum[tid] : 0;
    sh[tid] = v;
    __syncthreads();
#pragma unroll
    for (int off = 1; off < 256; off <<= 1) {
        int t = (tid >= off) ? sh[tid - off] : 0;
        __syncthreads();
        sh[tid] += t;
        __syncthreads();
    }
    if (tid < SCAN_BLOCKS) bsum[tid] = sh[tid] - v;  // exclusive block offsets
}

__global__ void k_scan3(int* __restrict__ row_ptr, const int* __restrict__ bsum) {
    const int b = blockIdx.x, tid = threadIdx.x;
    const int idx = b * 256 + tid;
    row_ptr[idx] += bsum[b];
    if (idx == 0) row_ptr[NV] = E_TOT;
}

// CSR fill: same 8-per-graph partition, LDS cursor seeded from row_ptr.
__launch_bounds__(1024)
__global__ void k_fill_lds(const int* __restrict__ ei, const float* __restrict__ ew,
                           const float* __restrict__ dinv, const int* __restrict__ row_ptr,
                           int* __restrict__ col_idx, float* __restrict__ val) {
    __shared__ int curl[DPB];
    const int b = blockIdx.x;
    const int g = b >> 3, part = b & 7;
    const int t0 = part * DPB;
    const int nbase = g * V_NODES + t0;
    const int tid = threadIdx.x;
    for (int i = tid; i < DPB; i += 1024) curl[i] = row_ptr[nbase + i];
    __syncthreads();
    const int*   src = ei + g * E_PER;
    const int*   tgt = ei + E_TOT + g * E_PER;
    const float* w   = ew + g * E_PER;
    for (int e = tid; e < E_PER; e += 1024) {
        int tl = tgt[e] - t0;
        if ((unsigned)tl < DPB) {
            int s = src[e] + g * V_NODES;
            int pos = atomicAdd(&curl[tl], 1);   // LDS atomic
            col_idx[pos] = s;
            val[pos] = dinv[s] * w[e] * dinv[nbase + tl];
        }
    }
}

// ---------------- weight convert: WT[n][k] = bf16(W[k][n]) for w1,w2 ------

__global__ void k_wt(const float* __restrict__ w1, const float* __restrict__ w2,
                     unsigned short* __restrict__ wt1, unsigned short* __restrict__ wt2) {
    int idx = blockIdx.x * 256 + threadIdx.x;     // 0 .. 2*512*512-1
    int which = idx >> 18;
    int rem = idx & 0x3ffff;
    int n = rem >> 9, k = rem & 511;
    const float* W = which ? w2 : w1;
    unsigned short* WT = which ? wt2 : wt1;
    WT[n * C + k] = f2bf(W[k * C + n]);
}

// ---------------- layer 0 (D_IN=1 collapse): scalar agg then expand -------

__global__ void k_agg0_scalar(const float* __restrict__ x, const int* __restrict__ row_ptr,
                              const int* __restrict__ col_idx, const float* __restrict__ val,
                              const float* __restrict__ dinv, float* __restrict__ s0) {
    int t = blockIdx.x * 256 + threadIdx.x;
    if (t >= NV) return;
    float dt = dinv[t];
    float acc = dt * dt * x[t];
    int e1 = row_ptr[t + 1];
    for (int e = row_ptr[t]; e < e1; e++)
        acc += val[e] * x[col_idx[e]];
    s0[t] = acc;
}

// h0 = bf16( LN( relu(s0*w0 + b0) ) )  — one block (128 thr) per node
__launch_bounds__(128)
__global__ void k_l0post(const float* __restrict__ s0, const float* __restrict__ w0,
                         const float* __restrict__ b0, const float* __restrict__ ln_g,
                         const float* __restrict__ ln_b, unsigned short* __restrict__ out) {
    const int t = blockIdx.x;
    const int tid = threadIdx.x;
    const int c4 = tid << 2;
    float s = s0[t];
    float4 w = *reinterpret_cast<const float4*>(&w0[c4]);
    float4 bb = *reinterpret_cast<const float4*>(&b0[c4]);
    float vx = fmaxf(s * w.x + bb.x, 0.f);
    float vy = fmaxf(s * w.y + bb.y, 0.f);
    float vz = fmaxf(s * w.z + bb.z, 0.f);
    float vw = fmaxf(s * w.w + bb.w, 0.f);
    __shared__ float redA[2], redB[2];
    float wsum = waveReduceSum(vx + vy + vz + vw);
    if ((tid & 63) == 0) redA[tid >> 6] = wsum;
    __syncthreads();
    float mu = (redA[0] + redA[1]) * (1.0f / C);
    float dx = vx - mu, dy = vy - mu, dz = vz - mu, dw = vw - mu;
    float wsq = waveReduceSum(dx * dx + dy * dy + dz * dz + dw * dw);
    if ((tid & 63) == 0) redB[tid >> 6] = wsq;
    __syncthreads();
    float rstd = rsqrtf((redB[0] + redB[1]) * (1.0f / C) + LN_EPS);
    float4 g = *reinterpret_cast<const float4*>(&ln_g[c4]);
    float4 b = *reinterpret_cast<const float4*>(&ln_b[c4]);
    ushort4 o = { f2bf(dx * rstd * g.x + b.x), f2bf(dy * rstd * g.y + b.y),
                  f2bf(dz * rstd * g.z + b.z), f2bf(dw * rstd * g.w + b.w) };
    reinterpret_cast<ushort4*>(out)[(size_t)t * 128 + tid] = o;
}

// ---------------- bf16 MFMA GEMM: Bout[M,N] = A[M,K] @ WT[N,K]^T ----------
// 128x128 tile, 4 waves (2x2 of 64x64), 16x16x32 MFMA, BK=32.
// Grid (M-tiles=288, N-tiles=4): dispatch idx = y*288+x, 288%8==0 -> all 4
// N-blocks sharing an A-panel land on the SAME XCD (A-panel L2 reuse).

__launch_bounds__(256)
__global__ void k_gemm_mfma(const unsigned short* __restrict__ A,
                            const unsigned short* __restrict__ WT,
                            unsigned short* __restrict__ Bout) {
    __shared__ short8 lA[512];
    __shared__ short8 lB[512];
    const int tid = threadIdx.x;
    const int lane = tid & 63;
    const int wave = tid >> 6;
    const int wr = wave >> 1, wc = wave & 1;
    const int l15 = lane & 15, kg = lane >> 4;
    const int m0 = blockIdx.x * 128;      // x = M block (288)
    const int n0 = blockIdx.y * 128;      // y = N block (4)

    floatx4 acc[4][4] = {};

    // staging: slot s = i*256 + tid, s -> (kgs = s>>7, idx = s&127)
    const int s0i = tid, s1i = 256 + tid;
    const int kgs0 = s0i >> 7, idx0 = s0i & 127;
    const int kgs1 = s1i >> 7, idx1 = s1i & 127;
    const unsigned short* gA0 = A + (size_t)(m0 + idx0) * C + kgs0 * 8;
    const unsigned short* gA1 = A + (size_t)(m0 + idx1) * C + kgs1 * 8;
    const unsigned short* gB0 = WT + (size_t)(n0 + idx0) * C + kgs0 * 8;
    const unsigned short* gB1 = WT + (size_t)(n0 + idx1) * C + kgs1 * 8;

    for (int k0 = 0; k0 < C; k0 += 32) {
        __builtin_amdgcn_global_load_lds((v_g*)(gA0 + k0), (v_l*)&lA[s0i], 16, 0, 0);
        __builtin_amdgcn_global_load_lds((v_g*)(gA1 + k0), (v_l*)&lA[s1i], 16, 0, 0);
        __builtin_amdgcn_global_load_lds((v_g*)(gB0 + k0), (v_l*)&lB[s0i], 16, 0, 0);
        __builtin_amdgcn_global_load_lds((v_g*)(gB1 + k0), (v_l*)&lB[s1i], 16, 0, 0);
        asm volatile("s_waitcnt vmcnt(0)" ::: "memory");
        __syncthreads();

        short8 af[4], bf[4];
#pragma unroll
        for (int mi = 0; mi < 4; mi++)
            af[mi] = lA[kg * 128 + wr * 64 + mi * 16 + l15];
#pragma unroll
        for (int ni = 0; ni < 4; ni++)
            bf[ni] = lB[kg * 128 + wc * 64 + ni * 16 + l15];
#pragma unroll
        for (int mi = 0; mi < 4; mi++)
#pragma unroll
            for (int ni = 0; ni < 4; ni++)
                acc[mi][ni] = __builtin_amdgcn_mfma_f32_16x16x32_bf16(
                    af[mi], bf[ni], acc[mi][ni], 0, 0, 0);
        __syncthreads();
    }

    // D layout: col = lane&15, row = (lane>>4)*4 + reg   [m89-verified]
#pragma unroll
    for (int mi = 0; mi < 4; mi++) {
#pragma unroll
        for (int ni = 0; ni < 4; ni++) {
            int n = n0 + wc * 64 + ni * 16 + l15;
#pragma unroll
            for (int r = 0; r < 4; r++) {
                int m = m0 + wr * 64 + mi * 16 + kg * 4 + r;
                Bout[(size_t)m * C + n] = f2bf(acc[mi][ni][r]);
            }
        }
    }
}

// ---------------- aggregate: ONE WAVE PER NODE, no barriers ---------------
// 64 lanes x ushort8 (16B) = full 512-ch row per wave. Edge idx/val are
// wave-uniform loads (SMEM path). 4 nodes per 256-thr block; grid 9216%8==0
// keeps graph g -> XCD g pinning (per-XCD gather set 4.6 MB ~ L2).

__launch_bounds__(256)
__global__ void k_agg(const unsigned short* __restrict__ hw, const int* __restrict__ row_ptr,
                      const int* __restrict__ col_idx, const float* __restrict__ val,
                      const float* __restrict__ dinv, const float* __restrict__ bias,
                      const float* __restrict__ ln_g, const float* __restrict__ ln_b,
                      unsigned short* __restrict__ out) {
    const int b = blockIdx.x;
    const int wv = threadIdx.x >> 6;
    const int lane = threadIdx.x & 63;
    const int t = (b & 7) * V_NODES + ((b >> 3) << 2) + wv;   // bijective
    const int e0 = row_ptr[t], e1 = row_ptr[t + 1];
    const short8* hw8 = reinterpret_cast<const short8*>(hw);

    const float dt = dinv[t];
    const float selfw = dt * dt;
    short8 hs = hw8[(size_t)t * 64 + lane];
    float a[8];
#pragma unroll
    for (int i = 0; i < 8; i++) a[i] = selfw * bf2f((unsigned short)hs[i]);

    int e = e0;
    for (; e + 4 <= e1; e += 4) {                 // 4 gathers in flight
        int i0 = col_idx[e], i1 = col_idx[e + 1], i2 = col_idx[e + 2], i3 = col_idx[e + 3];
        float w0 = val[e], w1 = val[e + 1], w2 = val[e + 2], w3 = val[e + 3];
        short8 h0 = hw8[(size_t)i0 * 64 + lane];
        short8 h1 = hw8[(size_t)i1 * 64 + lane];
        short8 h2 = hw8[(size_t)i2 * 64 + lane];
        short8 h3 = hw8[(size_t)i3 * 64 + lane];
#pragma unroll
        for (int i = 0; i < 8; i++) a[i] += w0 * bf2f((unsigned short)h0[i]);
#pragma unroll
        for (int i = 0; i < 8; i++) a[i] += w1 * bf2f((unsigned short)h1[i]);
#pragma unroll
        for (int i = 0; i < 8; i++) a[i] += w2 * bf2f((unsigned short)h2[i]);
#pragma unroll
        for (int i = 0; i < 8; i++) a[i] += w3 * bf2f((unsigned short)h3[i]);
    }
    for (; e < e1; e++) {
        int is = col_idx[e];
        float w = val[e];
        short8 hv = hw8[(size_t)is * 64 + lane];
#pragma unroll
        for (int i = 0; i < 8; i++) a[i] += w * bf2f((unsigned short)hv[i]);
    }

    // bias + relu
    const int c8 = lane << 3;
    float4 bb0 = *reinterpret_cast<const float4*>(&bias[c8]);
    float4 bb1 = *reinterpret_cast<const float4*>(&bias[c8 + 4]);
    a[0] = fmaxf(a[0] + bb0.x, 0.f); a[1] = fmaxf(a[1] + bb0.y, 0.f);
    a[2] = fmaxf(a[2] + bb0.z, 0.f); a[3] = fmaxf(a[3] + bb0.w, 0.f);
    a[4] = fmaxf(a[4] + bb1.x, 0.f); a[5] = fmaxf(a[5] + bb1.y, 0.f);
    a[6] = fmaxf(a[6] + bb1.z, 0.f); a[7] = fmaxf(a[7] + bb1.w, 0.f);

    // layernorm, wave-local (no barriers)
    float s = a[0] + a[1] + a[2] + a[3] + a[4] + a[5] + a[6] + a[7];
    float mu = waveAllSum(s) * (1.0f / C);
    float sq = 0.f;
#pragma unroll
    for (int i = 0; i < 8; i++) { float d = a[i] - mu; sq += d * d; }
    float rstd = rsqrtf(waveAllSum(sq) * (1.0f / C) + LN_EPS);

    float4 g0 = *reinterpret_cast<const float4*>(&ln_g[c8]);
    float4 g1 = *reinterpret_cast<const float4*>(&ln_g[c8 + 4]);
    float4 z0 = *reinterpret_cast<const float4*>(&ln_b[c8]);
    float4 z1 = *reinterpret_cast<const float4*>(&ln_b[c8 + 4]);
    short8 o;
    o[0] = (short)f2bf((a[0] - mu) * rstd * g0.x + z0.x);
    o[1] = (short)f2bf((a[1] - mu) * rstd * g0.y + z0.y);
    o[2] = (short)f2bf((a[2] - mu) * rstd * g0.z + z0.z);
    o[3] = (short)f2bf((a[3] - mu) * rstd * g0.w + z0.w);
    o[4] = (short)f2bf((a[4] - mu) * rstd * g1.x + z1.x);
    o[5] = (short)f2bf((a[5] - mu) * rstd * g1.y + z1.y);
    o[6] = (short)f2bf((a[6] - mu) * rstd * g1.z + z1.z);
    o[7] = (short)f2bf((a[7] - mu) * rstd * g1.w + z1.w);
    reinterpret_cast<short8*>(out)[(size_t)t * 64 + lane] = o;
}

// ---------------- pooling + final LN + head ----------------

__global__ void k_pool1(const unsigned short* __restrict__ h, float* __restrict__ pmax) {
    int g = blockIdx.x, chunk = blockIdx.y;
    int c = threadIdx.x;  // 512
    int r0 = g * V_NODES + chunk * 128;
    float m = -1e30f;
#pragma unroll 4
    for (int r = 0; r < 128; r++)
        m = fmaxf(m, bf2f(h[(size_t)(r0 + r) * C + c]));
    pmax[((size_t)g * POOL_CHUNKS + chunk) * C + c] = m;
}

__global__ void k_pool2_head(const float* __restrict__ pmax, const float* __restrict__ ln_g,
                             const float* __restrict__ ln_b, const float* __restrict__ hw,
                             const float* __restrict__ hb, float* __restrict__ out) {
    __shared__ float sred[8];
    int g = blockIdx.x;
    int c = threadIdx.x;  // 512
    float m = -1e30f;
#pragma unroll
    for (int j = 0; j < POOL_CHUNKS; j++)
        m = fmaxf(m, pmax[((size_t)g * POOL_CHUNKS + j) * C + c]);
    float total = blockSum512(m, sred);
    float mu = total * (1.0f / C);
    float d = m - mu;
    float var = blockSum512(d * d, sred) * (1.0f / C);
    float rstd = rsqrtf(var + LN_EPS);
    float p = d * rstd * ln_g[c] + ln_b[c];
    float r0 = blockSum512(p * hw[c * NCLS + 0], sred);
    float r1 = blockSum512(p * hw[c * NCLS + 1], sred);
    float r2 = blockSum512(p * hw[c * NCLS + 2], sred);
    if (threadIdx.x == 0) {
        out[g * NCLS + 0] = r0 + hb[0];
        out[g * NCLS + 1] = r1 + hb[1];
        out[g * NCLS + 2] = r2 + hb[2];
    }
}

// ---------------- launch ----------------

extern "C" void kernel_launch(void* const* d_in, const int* in_sizes, int n_in,
                              void* d_out, int out_size, void* d_ws, size_t ws_size,
                              hipStream_t stream) {
    const float* x      = (const float*)d_in[0];
    const float* ew     = (const float*)d_in[1];
    const float* w0     = (const float*)d_in[2];
    const float* b0     = (const float*)d_in[3];
    const float* w1     = (const float*)d_in[4];
    const float* b1     = (const float*)d_in[5];
    const float* w2     = (const float*)d_in[6];
    const float* b2     = (const float*)d_in[7];
    const float* ln_g   = (const float*)d_in[8];
    const float* ln_b   = (const float*)d_in[9];
    const float* head_w = (const float*)d_in[10];
    const float* head_b = (const float*)d_in[11];
    const int*   ei     = (const int*)d_in[12];
    float* out = (float*)d_out;

    char* p = (char*)d_ws;
    auto alloc = [&](size_t bytes) { void* r = p; p += (bytes + 255) & ~255ull; return r; };
    unsigned short* bufA = (unsigned short*)alloc((size_t)NV * C * 2);
    unsigned short* bufB = (unsigned short*)alloc((size_t)NV * C * 2);
    unsigned short* wt1  = (unsigned short*)alloc((size_t)C * C * 2);
    unsigned short* wt2  = (unsigned short*)alloc((size_t)C * C * 2);
    float* s0      = (float*)alloc((size_t)NV * 4);
    float* dinv    = (float*)alloc((size_t)NV * 4);
    int*   counts  = (int*)alloc((size_t)NV * 4);
    int*   row_ptr = (int*)alloc((size_t)(NV + 1) * 4);
    int*   bsum    = (int*)alloc((size_t)SCAN_BLOCKS * 4);
    int*   col_idx = (int*)alloc((size_t)E_TOT * 4);
    float* val     = (float*)alloc((size_t)E_TOT * 4);
    float* pmax    = (float*)alloc((size_t)N_GRAPH * POOL_CHUNKS * C * 4);

    // graph preprocessing (no global atomics)
    k_deg_lds<<<64, 1024, 0, stream>>>(ei, ew, dinv, counts);
    k_scan1<<<SCAN_BLOCKS, 256, 0, stream>>>(counts, row_ptr, bsum);
    k_scan2<<<1, 256, 0, stream>>>(bsum);
    k_scan3<<<SCAN_BLOCKS, 256, 0, stream>>>(row_ptr, bsum);
    k_fill_lds<<<64, 1024, 0, stream>>>(ei, ew, dinv, row_ptr, col_idx, val);
    k_wt<<<(2 * C * C) / 256, 256, 0, stream>>>(w1, w2, wt1, wt2);

    // layer 0 (collapsed: scalar agg, then expand+LN)
    k_agg0_scalar<<<NV / 256, 256, 0, stream>>>(x, row_ptr, col_idx, val, dinv, s0);
    k_l0post<<<NV, 128, 0, stream>>>(s0, w0, b0, ln_g, ln_b, bufA);

    // layer 1
    k_gemm_mfma<<<dim3(NV / 128, C / 128), 256, 0, stream>>>(bufA, wt1, bufB);
    k_agg<<<NV / 4, 256, 0, stream>>>(bufB, row_ptr, col_idx, val, dinv, b1, ln_g, ln_b, bufA);

    // layer 2
    k_gemm_mfma<<<dim3(NV / 128, C / 128), 256, 0, stream>>>(bufA, wt2, bufB);
    k_agg<<<NV / 4, 256, 0, stream>>>(bufB, row_ptr, col_idx, val, dinv, b2, ln_g, ln_b, bufA);

    // pooling + head
    k_pool1<<<dim3(N_GRAPH, POOL_CHUNKS), C, 0, stream>>>(bufA, pmax);
    k_pool2_head<<<N_GRAPH, C, 0, stream>>>(pmax, ln_g, ln_b, head_w, head_b, out);
}

// Round 11
// 375.719 us; speedup vs baseline: 1.2047x; 1.2047x over previous
//
#include <hip/hip_runtime.h>
#include <hip/hip_bf16.h>
#include <stdint.h>

#define N_GRAPH 8
#define V_NODES 4608
#define E_PER   73728
#define NV      (N_GRAPH * V_NODES)   // 36864
#define E_TOT   (N_GRAPH * E_PER)     // 589824
#define C       512
#define NCLS    3
#define LN_EPS  1e-5f
#define POOL_CHUNKS 36                // V_NODES / 128
#define SCAN_BLOCKS 144               // NV / 256
#define SUBB    32                    // sub-blocks per graph
#define EPSB    (E_PER / SUBB)        // 2304 edges per sub-block

typedef __attribute__((ext_vector_type(8))) short short8;
typedef __attribute__((ext_vector_type(4))) float floatx4;
typedef __attribute__((address_space(1))) void v_g;
typedef __attribute__((address_space(3))) void v_l;

// ---------------- helpers ----------------

__device__ inline float waveReduceSum(float v) {
#pragma unroll
    for (int o = 32; o > 0; o >>= 1) v += __shfl_down(v, o, 64);
    return v; // valid on lane 0
}

__device__ inline float waveAllSum(float v) {   // butterfly: all lanes get total
#pragma unroll
    for (int o = 32; o > 0; o >>= 1) v += __shfl_xor(v, o, 64);
    return v;
}

__device__ inline float blockSum512(float v, volatile float* sred) {
    float s = waveReduceSum(v);
    if ((threadIdx.x & 63) == 0) sred[threadIdx.x >> 6] = s;
    __syncthreads();
    float t = 0.f;
#pragma unroll
    for (int i = 0; i < 8; i++) t += sred[i];
    __syncthreads();
    return t;
}

__device__ inline unsigned short f2bf(float f) {   // RNE
    uint32_t u = __float_as_uint(f);
    u += 0x7fffu + ((u >> 16) & 1u);
    return (unsigned short)(u >> 16);
}
__device__ inline float bf2f(unsigned short b) {
    return __uint_as_float(((uint32_t)b) << 16);
}

// ------ preprocessing: per-sub-block LDS histograms, zero global atomics ---
// 256 blocks (8 graphs x 32 sub-blocks), 256 threads. Block (g,j) owns 2304
// contiguous edges of graph g; histogram over the graph's 4608 targets in LDS.

__launch_bounds__(256)
__global__ void k_hist(const int* __restrict__ ei, const float* __restrict__ ew,
                       int* __restrict__ hist_c, float* __restrict__ hist_d) {
    __shared__ int   lcnt[V_NODES];
    __shared__ float ldeg[V_NODES];
    const int g = blockIdx.x >> 5, j = blockIdx.x & 31;
    const int tid = threadIdx.x;
    for (int i = tid; i < V_NODES; i += 256) { lcnt[i] = 0; ldeg[i] = 0.f; }
    __syncthreads();
    const int ebase = g * E_PER + j * EPSB;
    const int*   tgt = ei + E_TOT + ebase;
    const float* w   = ew + ebase;
    for (int i = tid; i < EPSB; i += 256) {
        int t = tgt[i];
        atomicAdd(&lcnt[t], 1);
        atomicAdd(&ldeg[t], w[i]);
    }
    __syncthreads();
    const size_t hb = ((size_t)g * SUBB + j) * V_NODES;
    for (int i = tid; i < V_NODES; i += 256) {
        hist_c[hb + i] = lcnt[i];
        hist_d[hb + i] = ldeg[i];
    }
}

// per node: counts = sum_j hist_c, dinv = rsqrt(1 + sum_j hist_d);
// hist_c[g][j][t] <- exclusive prefix over j (relative offsets).
__global__ void k_reduce(int* __restrict__ hist_c, const float* __restrict__ hist_d,
                         int* __restrict__ counts, float* __restrict__ dinv) {
    const int node = blockIdx.x * 256 + threadIdx.x;
    if (node >= NV) return;
    const int g = node / V_NODES, t = node - g * V_NODES;
    const size_t base = (size_t)g * SUBB * V_NODES + t;
    int c = 0;
    float d = 1.0f;                       // self-loop weight
#pragma unroll 8
    for (int j = 0; j < SUBB; j++) {
        const size_t idx = base + (size_t)j * V_NODES;
        int cc = hist_c[idx];
        hist_c[idx] = c;
        c += cc;
        d += hist_d[idx];
    }
    counts[node] = c;
    dinv[node] = rsqrtf(d);
}

// ---- multi-block exclusive scan of counts -> row_ptr (3 small kernels) ----

__global__ void k_scan1(const int* __restrict__ counts, int* __restrict__ row_ptr,
                        int* __restrict__ bsum) {
    __shared__ int sh[256];
    const int b = blockIdx.x, tid = threadIdx.x;
    const int idx = b * 256 + tid;
    int v = counts[idx];
    sh[tid] = v;
    __syncthreads();
#pragma unroll
    for (int off = 1; off < 256; off <<= 1) {
        int t = (tid >= off) ? sh[tid - off] : 0;
        __syncthreads();
        sh[tid] += t;
        __syncthreads();
    }
    row_ptr[idx] = sh[tid] - v;            // exclusive within block
    if (tid == 255) bsum[b] = sh[255];     // block total
}

__global__ void k_scan2(int* __restrict__ bsum) {   // 1 block, 256 threads
    __shared__ int sh[256];
    const int tid = threadIdx.x;
    int v = (tid < SCAN_BLOCKS) ? bsum[tid] : 0;
    sh[tid] = v;
    __syncthreads();
#pragma unroll
    for (int off = 1; off < 256; off <<= 1) {
        int t = (tid >= off) ? sh[tid - off] : 0;
        __syncthreads();
        sh[tid] += t;
        __syncthreads();
    }
    if (tid < SCAN_BLOCKS) bsum[tid] = sh[tid] - v;  // exclusive block offsets
}

__global__ void k_scan3(int* __restrict__ row_ptr, const int* __restrict__ bsum) {
    const int b = blockIdx.x, tid = threadIdx.x;
    const int idx = b * 256 + tid;
    row_ptr[idx] += bsum[b];
    if (idx == 0) row_ptr[NV] = E_TOT;
}

// CSR fill: block (g,j) re-reads its 2304 edges; LDS cursor = row_ptr + prefix.
__launch_bounds__(256)
__global__ void k_fill2(const int* __restrict__ ei, const float* __restrict__ ew,
                        const float* __restrict__ dinv, const int* __restrict__ row_ptr,
                        const int* __restrict__ hist_c,
                        int* __restrict__ col_idx, float* __restrict__ val) {
    __shared__ int cur[V_NODES];
    const int g = blockIdx.x >> 5, j = blockIdx.x & 31;
    const int tid = threadIdx.x;
    const int gV = g * V_NODES;
    const size_t hb = ((size_t)g * SUBB + j) * V_NODES;
    for (int i = tid; i < V_NODES; i += 256)
        cur[i] = row_ptr[gV + i] + hist_c[hb + i];
    __syncthreads();
    const int ebase = g * E_PER + j * EPSB;
    const int*   src = ei + ebase;
    const int*   tgt = ei + E_TOT + ebase;
    const float* w   = ew + ebase;
    for (int i = tid; i < EPSB; i += 256) {
        int t = tgt[i];
        int s = src[i] + gV;
        int pos = atomicAdd(&cur[t], 1);     // LDS atomic
        col_idx[pos] = s;
        val[pos] = dinv[s] * w[i] * dinv[gV + t];
    }
}

// ---------------- weight convert: WT[n][k] = bf16(W[k][n]) for w1,w2 ------

__global__ void k_wt(const float* __restrict__ w1, const float* __restrict__ w2,
                     unsigned short* __restrict__ wt1, unsigned short* __restrict__ wt2) {
    int idx = blockIdx.x * 256 + threadIdx.x;     // 0 .. 2*512*512-1
    int which = idx >> 18;
    int rem = idx & 0x3ffff;
    int n = rem >> 9, k = rem & 511;
    const float* W = which ? w2 : w1;
    unsigned short* WT = which ? wt2 : wt1;
    WT[n * C + k] = f2bf(W[k * C + n]);
}

// ---------------- layer 0 (D_IN=1 collapse): scalar agg then expand -------

__global__ void k_agg0_scalar(const float* __restrict__ x, const int* __restrict__ row_ptr,
                              const int* __restrict__ col_idx, const float* __restrict__ val,
                              const float* __restrict__ dinv, float* __restrict__ s0) {
    int t = blockIdx.x * 256 + threadIdx.x;
    if (t >= NV) return;
    float dt = dinv[t];
    float acc = dt * dt * x[t];
    int e1 = row_ptr[t + 1];
    for (int e = row_ptr[t]; e < e1; e++)
        acc += val[e] * x[col_idx[e]];
    s0[t] = acc;
}

// h0 = bf16( LN( relu(s0*w0 + b0) ) )  — one block (128 thr) per node
__launch_bounds__(128)
__global__ void k_l0post(const float* __restrict__ s0, const float* __restrict__ w0,
                         const float* __restrict__ b0, const float* __restrict__ ln_g,
                         const float* __restrict__ ln_b, unsigned short* __restrict__ out) {
    const int t = blockIdx.x;
    const int tid = threadIdx.x;
    const int c4 = tid << 2;
    float s = s0[t];
    float4 w = *reinterpret_cast<const float4*>(&w0[c4]);
    float4 bb = *reinterpret_cast<const float4*>(&b0[c4]);
    float vx = fmaxf(s * w.x + bb.x, 0.f);
    float vy = fmaxf(s * w.y + bb.y, 0.f);
    float vz = fmaxf(s * w.z + bb.z, 0.f);
    float vw = fmaxf(s * w.w + bb.w, 0.f);
    __shared__ float redA[2], redB[2];
    float wsum = waveReduceSum(vx + vy + vz + vw);
    if ((tid & 63) == 0) redA[tid >> 6] = wsum;
    __syncthreads();
    float mu = (redA[0] + redA[1]) * (1.0f / C);
    float dx = vx - mu, dy = vy - mu, dz = vz - mu, dw = vw - mu;
    float wsq = waveReduceSum(dx * dx + dy * dy + dz * dz + dw * dw);
    if ((tid & 63) == 0) redB[tid >> 6] = wsq;
    __syncthreads();
    float rstd = rsqrtf((redB[0] + redB[1]) * (1.0f / C) + LN_EPS);
    float4 g = *reinterpret_cast<const float4*>(&ln_g[c4]);
    float4 b = *reinterpret_cast<const float4*>(&ln_b[c4]);
    ushort4 o = { f2bf(dx * rstd * g.x + b.x), f2bf(dy * rstd * g.y + b.y),
                  f2bf(dz * rstd * g.z + b.z), f2bf(dw * rstd * g.w + b.w) };
    reinterpret_cast<ushort4*>(out)[(size_t)t * 128 + tid] = o;
}

// ---------------- bf16 MFMA GEMM: Bout[M,N] = A[M,K] @ WT[N,K]^T ----------
// 128x128 tile, 4 waves (2x2 of 64x64), 16x16x32 MFMA, BK=32.
// Grid (M-tiles=288, N-tiles=4): dispatch idx = y*288+x, 288%8==0 -> all 4
// N-blocks sharing an A-panel land on the SAME XCD (A-panel L2 reuse).

__launch_bounds__(256)
__global__ void k_gemm_mfma(const unsigned short* __restrict__ A,
                            const unsigned short* __restrict__ WT,
                            unsigned short* __restrict__ Bout) {
    __shared__ short8 lA[512];
    __shared__ short8 lB[512];
    const int tid = threadIdx.x;
    const int lane = tid & 63;
    const int wave = tid >> 6;
    const int wr = wave >> 1, wc = wave & 1;
    const int l15 = lane & 15, kg = lane >> 4;
    const int m0 = blockIdx.x * 128;      // x = M block (288)
    const int n0 = blockIdx.y * 128;      // y = N block (4)

    floatx4 acc[4][4] = {};

    // staging: slot s = i*256 + tid, s -> (kgs = s>>7, idx = s&127)
    const int s0i = tid, s1i = 256 + tid;
    const int kgs0 = s0i >> 7, idx0 = s0i & 127;
    const int kgs1 = s1i >> 7, idx1 = s1i & 127;
    const unsigned short* gA0 = A + (size_t)(m0 + idx0) * C + kgs0 * 8;
    const unsigned short* gA1 = A + (size_t)(m0 + idx1) * C + kgs1 * 8;
    const unsigned short* gB0 = WT + (size_t)(n0 + idx0) * C + kgs0 * 8;
    const unsigned short* gB1 = WT + (size_t)(n0 + idx1) * C + kgs1 * 8;

    for (int k0 = 0; k0 < C; k0 += 32) {
        __builtin_amdgcn_global_load_lds((v_g*)(gA0 + k0), (v_l*)&lA[s0i], 16, 0, 0);
        __builtin_amdgcn_global_load_lds((v_g*)(gA1 + k0), (v_l*)&lA[s1i], 16, 0, 0);
        __builtin_amdgcn_global_load_lds((v_g*)(gB0 + k0), (v_l*)&lB[s0i], 16, 0, 0);
        __builtin_amdgcn_global_load_lds((v_g*)(gB1 + k0), (v_l*)&lB[s1i], 16, 0, 0);
        asm volatile("s_waitcnt vmcnt(0)" ::: "memory");
        __syncthreads();

        short8 af[4], bf[4];
#pragma unroll
        for (int mi = 0; mi < 4; mi++)
            af[mi] = lA[kg * 128 + wr * 64 + mi * 16 + l15];
#pragma unroll
        for (int ni = 0; ni < 4; ni++)
            bf[ni] = lB[kg * 128 + wc * 64 + ni * 16 + l15];
#pragma unroll
        for (int mi = 0; mi < 4; mi++)
#pragma unroll
            for (int ni = 0; ni < 4; ni++)
                acc[mi][ni] = __builtin_amdgcn_mfma_f32_16x16x32_bf16(
                    af[mi], bf[ni], acc[mi][ni], 0, 0, 0);
        __syncthreads();
    }

    // D layout: col = lane&15, row = (lane>>4)*4 + reg   [m89-verified]
#pragma unroll
    for (int mi = 0; mi < 4; mi++) {
#pragma unroll
        for (int ni = 0; ni < 4; ni++) {
            int n = n0 + wc * 64 + ni * 16 + l15;
#pragma unroll
            for (int r = 0; r < 4; r++) {
                int m = m0 + wr * 64 + mi * 16 + kg * 4 + r;
                Bout[(size_t)m * C + n] = f2bf(acc[mi][ni][r]);
            }
        }
    }
}

// ---------------- aggregate: ONE WAVE PER NODE, no barriers ---------------
// 64 lanes x ushort8 (16B) = full 512-ch row per wave. 4 nodes per 256-thr
// block; grid 9216%8==0 keeps graph g -> XCD g pinning (per-XCD set ~L2).

__launch_bounds__(256)
__global__ void k_agg(const unsigned short* __restrict__ hw, const int* __restrict__ row_ptr,
                      const int* __restrict__ col_idx, const float* __restrict__ val,
                      const float* __restrict__ dinv, const float* __restrict__ bias,
                      const float* __restrict__ ln_g, const float* __restrict__ ln_b,
                      unsigned short* __restrict__ out) {
    const int b = blockIdx.x;
    const int wv = threadIdx.x >> 6;
    const int lane = threadIdx.x & 63;
    const int t = (b & 7) * V_NODES + ((b >> 3) << 2) + wv;   // bijective
    const int e0 = row_ptr[t], e1 = row_ptr[t + 1];
    const short8* hw8 = reinterpret_cast<const short8*>(hw);

    const float dt = dinv[t];
    const float selfw = dt * dt;
    short8 hs = hw8[(size_t)t * 64 + lane];
    float a[8];
#pragma unroll
    for (int i = 0; i < 8; i++) a[i] = selfw * bf2f((unsigned short)hs[i]);

    int e = e0;
    for (; e + 4 <= e1; e += 4) {                 // 4 gathers in flight
        int i0 = col_idx[e], i1 = col_idx[e + 1], i2 = col_idx[e + 2], i3 = col_idx[e + 3];
        float w0 = val[e], w1 = val[e + 1], w2 = val[e + 2], w3 = val[e + 3];
        short8 h0 = hw8[(size_t)i0 * 64 + lane];
        short8 h1 = hw8[(size_t)i1 * 64 + lane];
        short8 h2 = hw8[(size_t)i2 * 64 + lane];
        short8 h3 = hw8[(size_t)i3 * 64 + lane];
#pragma unroll
        for (int i = 0; i < 8; i++) a[i] += w0 * bf2f((unsigned short)h0[i]);
#pragma unroll
        for (int i = 0; i < 8; i++) a[i] += w1 * bf2f((unsigned short)h1[i]);
#pragma unroll
        for (int i = 0; i < 8; i++) a[i] += w2 * bf2f((unsigned short)h2[i]);
#pragma unroll
        for (int i = 0; i < 8; i++) a[i] += w3 * bf2f((unsigned short)h3[i]);
    }
    for (; e < e1; e++) {
        int is = col_idx[e];
        float w = val[e];
        short8 hv = hw8[(size_t)is * 64 + lane];
#pragma unroll
        for (int i = 0; i < 8; i++) a[i] += w * bf2f((unsigned short)hv[i]);
    }

    // bias + relu
    const int c8 = lane << 3;
    float4 bb0 = *reinterpret_cast<const float4*>(&bias[c8]);
    float4 bb1 = *reinterpret_cast<const float4*>(&bias[c8 + 4]);
    a[0] = fmaxf(a[0] + bb0.x, 0.f); a[1] = fmaxf(a[1] + bb0.y, 0.f);
    a[2] = fmaxf(a[2] + bb0.z, 0.f); a[3] = fmaxf(a[3] + bb0.w, 0.f);
    a[4] = fmaxf(a[4] + bb1.x, 0.f); a[5] = fmaxf(a[5] + bb1.y, 0.f);
    a[6] = fmaxf(a[6] + bb1.z, 0.f); a[7] = fmaxf(a[7] + bb1.w, 0.f);

    // layernorm, wave-local (no barriers)
    float s = a[0] + a[1] + a[2] + a[3] + a[4] + a[5] + a[6] + a[7];
    float mu = waveAllSum(s) * (1.0f / C);
    float sq = 0.f;
#pragma unroll
    for (int i = 0; i < 8; i++) { float d = a[i] - mu; sq += d * d; }
    float rstd = rsqrtf(waveAllSum(sq) * (1.0f / C) + LN_EPS);

    float4 g0 = *reinterpret_cast<const float4*>(&ln_g[c8]);
    float4 g1 = *reinterpret_cast<const float4*>(&ln_g[c8 + 4]);
    float4 z0 = *reinterpret_cast<const float4*>(&ln_b[c8]);
    float4 z1 = *reinterpret_cast<const float4*>(&ln_b[c8 + 4]);
    short8 o;
    o[0] = (short)f2bf((a[0] - mu) * rstd * g0.x + z0.x);
    o[1] = (short)f2bf((a[1] - mu) * rstd * g0.y + z0.y);
    o[2] = (short)f2bf((a[2] - mu) * rstd * g0.z + z0.z);
    o[3] = (short)f2bf((a[3] - mu) * rstd * g0.w + z0.w);
    o[4] = (short)f2bf((a[4] - mu) * rstd * g1.x + z1.x);
    o[5] = (short)f2bf((a[5] - mu) * rstd * g1.y + z1.y);
    o[6] = (short)f2bf((a[6] - mu) * rstd * g1.z + z1.z);
    o[7] = (short)f2bf((a[7] - mu) * rstd * g1.w + z1.w);
    reinterpret_cast<short8*>(out)[(size_t)t * 64 + lane] = o;
}

// ---------------- pooling + final LN + head ----------------

__global__ void k_pool1(const unsigned short* __restrict__ h, float* __restrict__ pmax) {
    int g = blockIdx.x, chunk = blockIdx.y;
    int c = threadIdx.x;  // 512
    int r0 = g * V_NODES + chunk * 128;
    float m = -1e30f;
#pragma unroll 4
    for (int r = 0; r < 128; r++)
        m = fmaxf(m, bf2f(h[(size_t)(r0 + r) * C + c]));
    pmax[((size_t)g * POOL_CHUNKS + chunk) * C + c] = m;
}

__global__ void k_pool2_head(const float* __restrict__ pmax, const float* __restrict__ ln_g,
                             const float* __restrict__ ln_b, const float* __restrict__ hw,
                             const float* __restrict__ hb, float* __restrict__ out) {
    __shared__ float sred[8];
    int g = blockIdx.x;
    int c = threadIdx.x;  // 512
    float m = -1e30f;
#pragma unroll
    for (int j = 0; j < POOL_CHUNKS; j++)
        m = fmaxf(m, pmax[((size_t)g * POOL_CHUNKS + j) * C + c]);
    float total = blockSum512(m, sred);
    float mu = total * (1.0f / C);
    float d = m - mu;
    float var = blockSum512(d * d, sred) * (1.0f / C);
    float rstd = rsqrtf(var + LN_EPS);
    float p = d * rstd * ln_g[c] + ln_b[c];
    float r0 = blockSum512(p * hw[c * NCLS + 0], sred);
    float r1 = blockSum512(p * hw[c * NCLS + 1], sred);
    float r2 = blockSum512(p * hw[c * NCLS + 2], sred);
    if (threadIdx.x == 0) {
        out[g * NCLS + 0] = r0 + hb[0];
        out[g * NCLS + 1] = r1 + hb[1];
        out[g * NCLS + 2] = r2 + hb[2];
    }
}

// ---------------- launch ----------------

extern "C" void kernel_launch(void* const* d_in, const int* in_sizes, int n_in,
                              void* d_out, int out_size, void* d_ws, size_t ws_size,
                              hipStream_t stream) {
    const float* x      = (const float*)d_in[0];
    const float* ew     = (const float*)d_in[1];
    const float* w0     = (const float*)d_in[2];
    const float* b0     = (const float*)d_in[3];
    const float* w1     = (const float*)d_in[4];
    const float* b1     = (const float*)d_in[5];
    const float* w2     = (const float*)d_in[6];
    const float* b2     = (const float*)d_in[7];
    const float* ln_g   = (const float*)d_in[8];
    const float* ln_b   = (const float*)d_in[9];
    const float* head_w = (const float*)d_in[10];
    const float* head_b = (const float*)d_in[11];
    const int*   ei     = (const int*)d_in[12];
    float* out = (float*)d_out;

    char* p = (char*)d_ws;
    auto alloc = [&](size_t bytes) { void* r = p; p += (bytes + 255) & ~255ull; return r; };
    unsigned short* bufA = (unsigned short*)alloc((size_t)NV * C * 2);
    unsigned short* bufB = (unsigned short*)alloc((size_t)NV * C * 2);
    unsigned short* wt1  = (unsigned short*)alloc((size_t)C * C * 2);
    unsigned short* wt2  = (unsigned short*)alloc((size_t)C * C * 2);
    float* s0      = (float*)alloc((size_t)NV * 4);
    float* dinv    = (float*)alloc((size_t)NV * 4);
    int*   counts  = (int*)alloc((size_t)NV * 4);
    int*   row_ptr = (int*)alloc((size_t)(NV + 1) * 4);
    int*   bsum    = (int*)alloc((size_t)SCAN_BLOCKS * 4);
    int*   hist_c  = (int*)alloc((size_t)N_GRAPH * SUBB * V_NODES * 4);
    float* hist_d  = (float*)alloc((size_t)N_GRAPH * SUBB * V_NODES * 4);
    int*   col_idx = (int*)alloc((size_t)E_TOT * 4);
    float* val     = (float*)alloc((size_t)E_TOT * 4);
    float* pmax    = (float*)alloc((size_t)N_GRAPH * POOL_CHUNKS * C * 4);

    // graph preprocessing (no global atomics, full-chip parallel)
    k_hist<<<N_GRAPH * SUBB, 256, 0, stream>>>(ei, ew, hist_c, hist_d);
    k_reduce<<<SCAN_BLOCKS, 256, 0, stream>>>(hist_c, hist_d, counts, dinv);
    k_scan1<<<SCAN_BLOCKS, 256, 0, stream>>>(counts, row_ptr, bsum);
    k_scan2<<<1, 256, 0, stream>>>(bsum);
    k_scan3<<<SCAN_BLOCKS, 256, 0, stream>>>(row_ptr, bsum);
    k_fill2<<<N_GRAPH * SUBB, 256, 0, stream>>>(ei, ew, dinv, row_ptr, hist_c, col_idx, val);
    k_wt<<<(2 * C * C) / 256, 256, 0, stream>>>(w1, w2, wt1, wt2);

    // layer 0 (collapsed: scalar agg, then expand+LN)
    k_agg0_scalar<<<NV / 256, 256, 0, stream>>>(x, row_ptr, col_idx, val, dinv, s0);
    k_l0post<<<NV, 128, 0, stream>>>(s0, w0, b0, ln_g, ln_b, bufA);

    // layer 1
    k_gemm_mfma<<<dim3(NV / 128, C / 128), 256, 0, stream>>>(bufA, wt1, bufB);
    k_agg<<<NV / 4, 256, 0, stream>>>(bufB, row_ptr, col_idx, val, dinv, b1, ln_g, ln_b, bufA);

    // layer 2
    k_gemm_mfma<<<dim3(NV / 128, C / 128), 256, 0, stream>>>(bufA, wt2, bufB);
    k_agg<<<NV / 4, 256, 0, stream>>>(bufB, row_ptr, col_idx, val, dinv, b2, ln_g, ln_b, bufA);

    // pooling + head
    k_pool1<<<dim3(N_GRAPH, POOL_CHUNKS), C, 0, stream>>>(bufA, pmax);
    k_pool2_head<<<N_GRAPH, C, 0, stream>>>(pmax, ln_g, ln_b, head_w, head_b, out);
}

// Round 13
// 369.368 us; speedup vs baseline: 1.2254x; 1.0172x over previous
//
#include <hip/hip_runtime.h>
#include <hip/hip_bf16.h>
#include <stdint.h>

#define N_GRAPH 8
#define V_NODES 4608
#define E_PER   73728
#define NV      (N_GRAPH * V_NODES)   // 36864
#define E_TOT   (N_GRAPH * E_PER)     // 589824
#define C       512
#define NCLS    3
#define LN_EPS  1e-5f
#define POOL_CHUNKS 36                // V_NODES / 128
#define POOL_PARTS  144               // POOL_CHUNKS * 4 waves
#define SCAN_BLOCKS 144               // NV / 256
#define SUBB    32                    // sub-blocks per graph
#define EPSB    (E_PER / SUBB)        // 2304 edges per sub-block

typedef __attribute__((ext_vector_type(8))) short short8;
typedef __attribute__((ext_vector_type(4))) float floatx4;
typedef __attribute__((ext_vector_type(2))) float float2v;
typedef __attribute__((address_space(1))) void v_g;
typedef __attribute__((address_space(3))) void v_l;

// ---------------- helpers ----------------

__device__ inline float waveReduceSum(float v) {
#pragma unroll
    for (int o = 32; o > 0; o >>= 1) v += __shfl_down(v, o, 64);
    return v; // valid on lane 0
}

__device__ inline float waveAllSum(float v) {   // butterfly: all lanes get total
#pragma unroll
    for (int o = 32; o > 0; o >>= 1) v += __shfl_xor(v, o, 64);
    return v;
}

__device__ inline float blockSum512(float v, volatile float* sred) {
    float s = waveReduceSum(v);
    if ((threadIdx.x & 63) == 0) sred[threadIdx.x >> 6] = s;
    __syncthreads();
    float t = 0.f;
#pragma unroll
    for (int i = 0; i < 8; i++) t += sred[i];
    __syncthreads();
    return t;
}

__device__ inline unsigned short f2bf(float f) {   // RNE
    uint32_t u = __float_as_uint(f);
    u += 0x7fffu + ((u >> 16) & 1u);
    return (unsigned short)(u >> 16);
}
__device__ inline float bf2f(unsigned short b) {
    return __uint_as_float(((uint32_t)b) << 16);
}

// ---- fp8 e4m3fn pack/unpack (HW cvt on gfx950; guarded fallback) ----

#if __has_builtin(__builtin_amdgcn_cvt_pk_fp8_f32)
__device__ inline uint32_t pk_fp8(float a, float b) {
    return (uint32_t)__builtin_amdgcn_cvt_pk_fp8_f32(a, b, 0, false);
}
#else
__device__ inline uint32_t fp8_enc1(float f) {
    float a = fminf(fmaxf(f, -448.f), 448.f);
    uint32_t u = __float_as_uint(a);
    uint32_t s = (u >> 24) & 0x80;
    int e = (int)((u >> 23) & 0xff) - 127;
    uint32_t m = u & 0x7fffff;
    if (a == 0.f || e < -9) return s;
    if (e < -6) {                       // subnormal
        int sh = -6 - e;                // 1..3
        uint32_t full = 0x800000u | m;
        uint32_t q = full >> (20 + sh);
        uint32_t rem = full & ((1u << (20 + sh)) - 1);
        uint32_t half = 1u << (19 + sh);
        q += (rem > half || (rem == half && (q & 1)));
        return s | q;
    }
    uint32_t q = m >> 20;
    uint32_t rem = m & 0xfffff;
    q += (rem > 0x80000 || (rem == 0x80000 && (q & 1)));
    uint32_t v = ((uint32_t)(e + 7) << 3) + q;
    if (v > 0x7e) v = 0x7e;
    return s | v;
}
__device__ inline uint32_t pk_fp8(float a, float b) {
    return fp8_enc1(a) | (fp8_enc1(b) << 8);
}
#endif

#if __has_builtin(__builtin_amdgcn_cvt_pk_f32_fp8)
__device__ inline float2v up_fp8_lo(uint32_t w) { return __builtin_amdgcn_cvt_pk_f32_fp8((int)w, false); }
__device__ inline float2v up_fp8_hi(uint32_t w) { return __builtin_amdgcn_cvt_pk_f32_fp8((int)w, true); }
#else
__device__ inline float fp8_dec1(uint32_t b) {
    uint32_t s = (b >> 7) & 1u, e = (b >> 3) & 0xfu, m = b & 7u;
    float mag = e ? ldexpf(1.0f + (float)m * 0.125f, (int)e - 7)
                  : (float)m * 0.001953125f;     // m * 2^-9
    return s ? -mag : mag;
}
__device__ inline float2v up_fp8_lo(uint32_t w) {
    float2v r; r.x = fp8_dec1(w & 0xff); r.y = fp8_dec1((w >> 8) & 0xff); return r;
}
__device__ inline float2v up_fp8_hi(uint32_t w) {
    float2v r; r.x = fp8_dec1((w >> 16) & 0xff); r.y = fp8_dec1(w >> 24); return r;
}
#endif

// ------ preprocessing: per-sub-block LDS histograms, zero global atomics ---

__launch_bounds__(256)
__global__ void k_hist(const int* __restrict__ ei, const float* __restrict__ ew,
                       int* __restrict__ hist_c, float* __restrict__ hist_d) {
    __shared__ int   lcnt[V_NODES];
    __shared__ float ldeg[V_NODES];
    const int g = blockIdx.x >> 5, j = blockIdx.x & 31;
    const int tid = threadIdx.x;
    for (int i = tid; i < V_NODES; i += 256) { lcnt[i] = 0; ldeg[i] = 0.f; }
    __syncthreads();
    const int ebase = g * E_PER + j * EPSB;
    const int*   tgt = ei + E_TOT + ebase;
    const float* w   = ew + ebase;
    for (int i = tid; i < EPSB; i += 256) {
        int t = tgt[i];
        atomicAdd(&lcnt[t], 1);
        atomicAdd(&ldeg[t], w[i]);
    }
    __syncthreads();
    const size_t hb = ((size_t)g * SUBB + j) * V_NODES;
    for (int i = tid; i < V_NODES; i += 256) {
        hist_c[hb + i] = lcnt[i];
        hist_d[hb + i] = ldeg[i];
    }
}

__global__ void k_reduce(int* __restrict__ hist_c, const float* __restrict__ hist_d,
                         int* __restrict__ counts, float* __restrict__ dinv) {
    const int node = blockIdx.x * 256 + threadIdx.x;
    if (node >= NV) return;
    const int g = node / V_NODES, t = node - g * V_NODES;
    const size_t base = (size_t)g * SUBB * V_NODES + t;
    int c = 0;
    float d = 1.0f;                       // self-loop weight
#pragma unroll 8
    for (int j = 0; j < SUBB; j++) {
        const size_t idx = base + (size_t)j * V_NODES;
        int cc = hist_c[idx];
        hist_c[idx] = c;
        c += cc;
        d += hist_d[idx];
    }
    counts[node] = c;
    dinv[node] = rsqrtf(d);
}

// ---- multi-block exclusive scan of counts -> row_ptr (3 small kernels) ----

__global__ void k_scan1(const int* __restrict__ counts, int* __restrict__ row_ptr,
                        int* __restrict__ bsum) {
    __shared__ int sh[256];
    const int b = blockIdx.x, tid = threadIdx.x;
    const int idx = b * 256 + tid;
    int v = counts[idx];
    sh[tid] = v;
    __syncthreads();
#pragma unroll
    for (int off = 1; off < 256; off <<= 1) {
        int t = (tid >= off) ? sh[tid - off] : 0;
        __syncthreads();
        sh[tid] += t;
        __syncthreads();
    }
    row_ptr[idx] = sh[tid] - v;            // exclusive within block
    if (tid == 255) bsum[b] = sh[255];     // block total
}

__global__ void k_scan2(int* __restrict__ bsum) {   // 1 block, 256 threads
    __shared__ int sh[256];
    const int tid = threadIdx.x;
    int v = (tid < SCAN_BLOCKS) ? bsum[tid] : 0;
    sh[tid] = v;
    __syncthreads();
#pragma unroll
    for (int off = 1; off < 256; off <<= 1) {
        int t = (tid >= off) ? sh[tid - off] : 0;
        __syncthreads();
        sh[tid] += t;
        __syncthreads();
    }
    if (tid < SCAN_BLOCKS) bsum[tid] = sh[tid] - v;  // exclusive block offsets
}

__global__ void k_scan3(int* __restrict__ row_ptr, const int* __restrict__ bsum) {
    const int b = blockIdx.x, tid = threadIdx.x;
    const int idx = b * 256 + tid;
    row_ptr[idx] += bsum[b];
    if (idx == 0) row_ptr[NV] = E_TOT;
}

// CSR fill: block (g,j) re-reads its 2304 edges; LDS cursor = row_ptr + prefix.
__launch_bounds__(256)
__global__ void k_fill2(const int* __restrict__ ei, const float* __restrict__ ew,
                        const float* __restrict__ dinv, const int* __restrict__ row_ptr,
                        const int* __restrict__ hist_c,
                        int* __restrict__ col_idx, float* __restrict__ val) {
    __shared__ int cur[V_NODES];
    const int g = blockIdx.x >> 5, j = blockIdx.x & 31;
    const int tid = threadIdx.x;
    const int gV = g * V_NODES;
    const size_t hb = ((size_t)g * SUBB + j) * V_NODES;
    for (int i = tid; i < V_NODES; i += 256)
        cur[i] = row_ptr[gV + i] + hist_c[hb + i];
    __syncthreads();
    const int ebase = g * E_PER + j * EPSB;
    const int*   src = ei + ebase;
    const int*   tgt = ei + E_TOT + ebase;
    const float* w   = ew + ebase;
    for (int i = tid; i < EPSB; i += 256) {
        int t = tgt[i];
        int s = src[i] + gV;
        int pos = atomicAdd(&cur[t], 1);     // LDS atomic
        col_idx[pos] = s;
        val[pos] = dinv[s] * w[i] * dinv[gV + t];
    }
}

// ---------------- weight convert: WT[n][k] = bf16(W[k][n]) for w1,w2 ------

__global__ void k_wt(const float* __restrict__ w1, const float* __restrict__ w2,
                     unsigned short* __restrict__ wt1, unsigned short* __restrict__ wt2) {
    int idx = blockIdx.x * 256 + threadIdx.x;     // 0 .. 2*512*512-1
    int which = idx >> 18;
    int rem = idx & 0x3ffff;
    int n = rem >> 9, k = rem & 511;
    const float* W = which ? w2 : w1;
    unsigned short* WT = which ? wt2 : wt1;
    WT[n * C + k] = f2bf(W[k * C + n]);
}

// ---------------- layer 0 (D_IN=1 collapse): scalar agg then expand -------

__global__ void k_agg0_scalar(const float* __restrict__ x, const int* __restrict__ row_ptr,
                              const int* __restrict__ col_idx, const float* __restrict__ val,
                              const float* __restrict__ dinv, float* __restrict__ s0) {
    int t = blockIdx.x * 256 + threadIdx.x;
    if (t >= NV) return;
    float dt = dinv[t];
    float acc = dt * dt * x[t];
    int e1 = row_ptr[t + 1];
    for (int e = row_ptr[t]; e < e1; e++)
        acc += val[e] * x[col_idx[e]];
    s0[t] = acc;
}

// h0 = bf16( LN( relu(s0*w0 + b0) ) )  — one block (128 thr) per node
__launch_bounds__(128)
__global__ void k_l0post(const float* __restrict__ s0, const float* __restrict__ w0,
                         const float* __restrict__ b0, const float* __restrict__ ln_g,
                         const float* __restrict__ ln_b, unsigned short* __restrict__ out) {
    const int t = blockIdx.x;
    const int tid = threadIdx.x;
    const int c4 = tid << 2;
    float s = s0[t];
    float4 w = *reinterpret_cast<const float4*>(&w0[c4]);
    float4 bb = *reinterpret_cast<const float4*>(&b0[c4]);
    float vx = fmaxf(s * w.x + bb.x, 0.f);
    float vy = fmaxf(s * w.y + bb.y, 0.f);
    float vz = fmaxf(s * w.z + bb.z, 0.f);
    float vw = fmaxf(s * w.w + bb.w, 0.f);
    __shared__ float redA[2], redB[2];
    float wsum = waveReduceSum(vx + vy + vz + vw);
    if ((tid & 63) == 0) redA[tid >> 6] = wsum;
    __syncthreads();
    float mu = (redA[0] + redA[1]) * (1.0f / C);
    float dx = vx - mu, dy = vy - mu, dz = vz - mu, dw = vw - mu;
    float wsq = waveReduceSum(dx * dx + dy * dy + dz * dz + dw * dw);
    if ((tid & 63) == 0) redB[tid >> 6] = wsq;
    __syncthreads();
    float rstd = rsqrtf((redB[0] + redB[1]) * (1.0f / C) + LN_EPS);
    float4 g = *reinterpret_cast<const float4*>(&ln_g[c4]);
    float4 b = *reinterpret_cast<const float4*>(&ln_b[c4]);
    ushort4 o = { f2bf(dx * rstd * g.x + b.x), f2bf(dy * rstd * g.y + b.y),
                  f2bf(dz * rstd * g.z + b.z), f2bf(dw * rstd * g.w + b.w) };
    reinterpret_cast<ushort4*>(out)[(size_t)t * 128 + tid] = o;
}

// ---------------- bf16 MFMA GEMM: Bout(fp8) = A[M,K] @ WT[N,K]^T ----------
// 128x128 tile, 4 waves (2x2 of 64x64), 16x16x32 MFMA, BK=32.
// Epilogue packs f32 -> fp8 e4m3 (hw buffer halves the agg gather bytes).

__launch_bounds__(256)
__global__ void k_gemm_mfma(const unsigned short* __restrict__ A,
                            const unsigned short* __restrict__ WT,
                            uint8_t* __restrict__ Bout) {
    __shared__ short8 lA[512];
    __shared__ short8 lB[512];
    const int tid = threadIdx.x;
    const int lane = tid & 63;
    const int wave = tid >> 6;
    const int wr = wave >> 1, wc = wave & 1;
    const int l15 = lane & 15, kg = lane >> 4;
    const int m0 = blockIdx.x * 128;      // x = M block (288)
    const int n0 = blockIdx.y * 128;      // y = N block (4)

    floatx4 acc[4][4] = {};

    const int s0i = tid, s1i = 256 + tid;
    const int kgs0 = s0i >> 7, idx0 = s0i & 127;
    const int kgs1 = s1i >> 7, idx1 = s1i & 127;
    const unsigned short* gA0 = A + (size_t)(m0 + idx0) * C + kgs0 * 8;
    const unsigned short* gA1 = A + (size_t)(m0 + idx1) * C + kgs1 * 8;
    const unsigned short* gB0 = WT + (size_t)(n0 + idx0) * C + kgs0 * 8;
    const unsigned short* gB1 = WT + (size_t)(n0 + idx1) * C + kgs1 * 8;

    for (int k0 = 0; k0 < C; k0 += 32) {
        __builtin_amdgcn_global_load_lds((v_g*)(gA0 + k0), (v_l*)&lA[s0i], 16, 0, 0);
        __builtin_amdgcn_global_load_lds((v_g*)(gA1 + k0), (v_l*)&lA[s1i], 16, 0, 0);
        __builtin_amdgcn_global_load_lds((v_g*)(gB0 + k0), (v_l*)&lB[s0i], 16, 0, 0);
        __builtin_amdgcn_global_load_lds((v_g*)(gB1 + k0), (v_l*)&lB[s1i], 16, 0, 0);
        asm volatile("s_waitcnt vmcnt(0)" ::: "memory");
        __syncthreads();

        short8 af[4], bf[4];
#pragma unroll
        for (int mi = 0; mi < 4; mi++)
            af[mi] = lA[kg * 128 + wr * 64 + mi * 16 + l15];
#pragma unroll
        for (int ni = 0; ni < 4; ni++)
            bf[ni] = lB[kg * 128 + wc * 64 + ni * 16 + l15];
#pragma unroll
        for (int mi = 0; mi < 4; mi++)
#pragma unroll
            for (int ni = 0; ni < 4; ni++)
                acc[mi][ni] = __builtin_amdgcn_mfma_f32_16x16x32_bf16(
                    af[mi], bf[ni], acc[mi][ni], 0, 0, 0);
        __syncthreads();
    }

    // D layout: col = lane&15, row = (lane>>4)*4 + reg   [m89-verified]
#pragma unroll
    for (int mi = 0; mi < 4; mi++) {
#pragma unroll
        for (int ni = 0; ni < 4; ni++) {
            int n = n0 + wc * 64 + ni * 16 + l15;
            floatx4 v = acc[mi][ni];
            uint32_t p01 = pk_fp8(v[0], v[1]);
            uint32_t p23 = pk_fp8(v[2], v[3]);
            uint8_t* rp = Bout + (size_t)(m0 + wr * 64 + mi * 16 + kg * 4) * C + n;
            rp[0]     = (uint8_t)p01;
            rp[C]     = (uint8_t)(p01 >> 8);
            rp[2 * C] = (uint8_t)p23;
            rp[3 * C] = (uint8_t)(p23 >> 8);
        }
    }
}

// ---------------- aggregate: ONE WAVE PER NODE, fp8 gather ---------------
// 64 lanes x 8B (8 fp8) = full 512-ch row per wave. 4 nodes per 256-thr
// block; grid 9216%8==0 keeps graph g -> XCD g pinning (per-XCD set ~L2/2).

__launch_bounds__(256)
__global__ void k_agg(const uint8_t* __restrict__ hw, const int* __restrict__ row_ptr,
                      const int* __restrict__ col_idx, const float* __restrict__ val,
                      const float* __restrict__ dinv, const float* __restrict__ bias,
                      const float* __restrict__ ln_g, const float* __restrict__ ln_b,
                      unsigned short* __restrict__ out) {
    const int b = blockIdx.x;
    const int wv = threadIdx.x >> 6;
    const int lane = threadIdx.x & 63;
    const int t = (b & 7) * V_NODES + ((b >> 3) << 2) + wv;   // bijective
    const int e0 = row_ptr[t], e1 = row_ptr[t + 1];
    const uint2* hw8 = reinterpret_cast<const uint2*>(hw);    // 8 fp8 per lane

    const float dt = dinv[t];
    const float selfw = dt * dt;
    float a[8];
    {
        uint2 hv = hw8[(size_t)t * 64 + lane];
        float2v f01 = up_fp8_lo(hv.x), f23 = up_fp8_hi(hv.x);
        float2v f45 = up_fp8_lo(hv.y), f67 = up_fp8_hi(hv.y);
        a[0] = selfw * f01.x; a[1] = selfw * f01.y;
        a[2] = selfw * f23.x; a[3] = selfw * f23.y;
        a[4] = selfw * f45.x; a[5] = selfw * f45.y;
        a[6] = selfw * f67.x; a[7] = selfw * f67.y;
    }

    int e = e0;
    for (; e + 4 <= e1; e += 4) {                 // 4 gathers in flight
        int i0 = col_idx[e], i1 = col_idx[e + 1], i2 = col_idx[e + 2], i3 = col_idx[e + 3];
        float w0 = val[e], w1 = val[e + 1], w2 = val[e + 2], w3 = val[e + 3];
        uint2 h0 = hw8[(size_t)i0 * 64 + lane];
        uint2 h1 = hw8[(size_t)i1 * 64 + lane];
        uint2 h2 = hw8[(size_t)i2 * 64 + lane];
        uint2 h3 = hw8[(size_t)i3 * 64 + lane];
#define ACC8(hv, w) { \
        float2v q01 = up_fp8_lo(hv.x), q23 = up_fp8_hi(hv.x); \
        float2v q45 = up_fp8_lo(hv.y), q67 = up_fp8_hi(hv.y); \
        a[0] += (w) * q01.x; a[1] += (w) * q01.y; \
        a[2] += (w) * q23.x; a[3] += (w) * q23.y; \
        a[4] += (w) * q45.x; a[5] += (w) * q45.y; \
        a[6] += (w) * q67.x; a[7] += (w) * q67.y; }
        ACC8(h0, w0) ACC8(h1, w1) ACC8(h2, w2) ACC8(h3, w3)
    }
    for (; e < e1; e++) {
        int is = col_idx[e];
        float w = val[e];
        uint2 hv = hw8[(size_t)is * 64 + lane];
        ACC8(hv, w)
    }
#undef ACC8

    // bias + relu
    const int c8 = lane << 3;
    float4 bb0 = *reinterpret_cast<const float4*>(&bias[c8]);
    float4 bb1 = *reinterpret_cast<const float4*>(&bias[c8 + 4]);
    a[0] = fmaxf(a[0] + bb0.x, 0.f); a[1] = fmaxf(a[1] + bb0.y, 0.f);
    a[2] = fmaxf(a[2] + bb0.z, 0.f); a[3] = fmaxf(a[3] + bb0.w, 0.f);
    a[4] = fmaxf(a[4] + bb1.x, 0.f); a[5] = fmaxf(a[5] + bb1.y, 0.f);
    a[6] = fmaxf(a[6] + bb1.z, 0.f); a[7] = fmaxf(a[7] + bb1.w, 0.f);

    // layernorm, wave-local (no barriers)
    float s = a[0] + a[1] + a[2] + a[3] + a[4] + a[5] + a[6] + a[7];
    float mu = waveAllSum(s) * (1.0f / C);
    float sq = 0.f;
#pragma unroll
    for (int i = 0; i < 8; i++) { float d = a[i] - mu; sq += d * d; }
    float rstd = rsqrtf(waveAllSum(sq) * (1.0f / C) + LN_EPS);

    float4 g0 = *reinterpret_cast<const float4*>(&ln_g[c8]);
    float4 g1 = *reinterpret_cast<const float4*>(&ln_g[c8 + 4]);
    float4 z0 = *reinterpret_cast<const float4*>(&ln_b[c8]);
    float4 z1 = *reinterpret_cast<const float4*>(&ln_b[c8 + 4]);
    short8 o;
    o[0] = (short)f2bf((a[0] - mu) * rstd * g0.x + z0.x);
    o[1] = (short)f2bf((a[1] - mu) * rstd * g0.y + z0.y);
    o[2] = (short)f2bf((a[2] - mu) * rstd * g0.z + z0.z);
    o[3] = (short)f2bf((a[3] - mu) * rstd * g0.w + z0.w);
    o[4] = (short)f2bf((a[4] - mu) * rstd * g1.x + z1.x);
    o[5] = (short)f2bf((a[5] - mu) * rstd * g1.y + z1.y);
    o[6] = (short)f2bf((a[6] - mu) * rstd * g1.z + z1.z);
    o[7] = (short)f2bf((a[7] - mu) * rstd * g1.w + z1.w);
    reinterpret_cast<short8*>(out)[(size_t)t * 64 + lane] = o;
}

// ---------------- pooling + final LN + head ----------------
// pool1: 4-wave blocks, short8 row loads; one partial max per wave.

__launch_bounds__(256)
__global__ void k_pool1(const unsigned short* __restrict__ h, float* __restrict__ pmax) {
    const int g = blockIdx.x, chunk = blockIdx.y;
    const int wv = threadIdx.x >> 6, lane = threadIdx.x & 63;
    const short8* h8 = reinterpret_cast<const short8*>(h);
    const size_t r0 = (size_t)g * V_NODES + chunk * 128 + wv * 32;
    float m[8];
#pragma unroll
    for (int i = 0; i < 8; i++) m[i] = -1e30f;
    for (int r = 0; r < 32; r++) {
        short8 v = h8[(r0 + r) * 64 + lane];
#pragma unroll
        for (int i = 0; i < 8; i++) m[i] = fmaxf(m[i], bf2f((unsigned short)v[i]));
    }
    float* dst = pmax + ((size_t)(g * POOL_PARTS + chunk * 4 + wv)) * C + (lane << 3);
    float4 o0 = { m[0], m[1], m[2], m[3] };
    float4 o1 = { m[4], m[5], m[6], m[7] };
    *reinterpret_cast<float4*>(dst) = o0;
    *reinterpret_cast<float4*>(dst + 4) = o1;
}

__global__ void k_pool2_head(const float* __restrict__ pmax, const float* __restrict__ ln_g,
                             const float* __restrict__ ln_b, const float* __restrict__ hw,
                             const float* __restrict__ hb, float* __restrict__ out) {
    __shared__ float sred[8];
    int g = blockIdx.x;
    int c = threadIdx.x;  // 512
    float m = -1e30f;
    for (int j = 0; j < POOL_PARTS; j++)
        m = fmaxf(m, pmax[((size_t)g * POOL_PARTS + j) * C + c]);
    float total = blockSum512(m, sred);
    float mu = total * (1.0f / C);
    float d = m - mu;
    float var = blockSum512(d * d, sred) * (1.0f / C);
    float rstd = rsqrtf(var + LN_EPS);
    float p = d * rstd * ln_g[c] + ln_b[c];
    float r0 = blockSum512(p * hw[c * NCLS + 0], sred);
    float r1 = blockSum512(p * hw[c * NCLS + 1], sred);
    float r2 = blockSum512(p * hw[c * NCLS + 2], sred);
    if (threadIdx.x == 0) {
        out[g * NCLS + 0] = r0 + hb[0];
        out[g * NCLS + 1] = r1 + hb[1];
        out[g * NCLS + 2] = r2 + hb[2];
    }
}

// ---------------- launch ----------------

extern "C" void kernel_launch(void* const* d_in, const int* in_sizes, int n_in,
                              void* d_out, int out_size, void* d_ws, size_t ws_size,
                              hipStream_t stream) {
    const float* x      = (const float*)d_in[0];
    const float* ew     = (const float*)d_in[1];
    const float* w0     = (const float*)d_in[2];
    const float* b0     = (const float*)d_in[3];
    const float* w1     = (const float*)d_in[4];
    const float* b1     = (const float*)d_in[5];
    const float* w2     = (const float*)d_in[6];
    const float* b2     = (const float*)d_in[7];
    const float* ln_g   = (const float*)d_in[8];
    const float* ln_b   = (const float*)d_in[9];
    const float* head_w = (const float*)d_in[10];
    const float* head_b = (const float*)d_in[11];
    const int*   ei     = (const int*)d_in[12];
    float* out = (float*)d_out;

    char* p = (char*)d_ws;
    auto alloc = [&](size_t bytes) { void* r = p; p += (bytes + 255) & ~255ull; return r; };
    unsigned short* bufA = (unsigned short*)alloc((size_t)NV * C * 2);
    uint8_t*        bufF = (uint8_t*)alloc((size_t)NV * C);          // fp8 hw
    unsigned short* wt1  = (unsigned short*)alloc((size_t)C * C * 2);
    unsigned short* wt2  = (unsigned short*)alloc((size_t)C * C * 2);
    float* s0      = (float*)alloc((size_t)NV * 4);
    float* dinv    = (float*)alloc((size_t)NV * 4);
    int*   counts  = (int*)alloc((size_t)NV * 4);
    int*   row_ptr = (int*)alloc((size_t)(NV + 1) * 4);
    int*   bsum    = (int*)alloc((size_t)SCAN_BLOCKS * 4);
    int*   hist_c  = (int*)alloc((size_t)N_GRAPH * SUBB * V_NODES * 4);
    float* hist_d  = (float*)alloc((size_t)N_GRAPH * SUBB * V_NODES * 4);
    int*   col_idx = (int*)alloc((size_t)E_TOT * 4);
    float* val     = (float*)alloc((size_t)E_TOT * 4);
    float* pmax    = (float*)alloc((size_t)N_GRAPH * POOL_PARTS * C * 4);

    // graph preprocessing (no global atomics, full-chip parallel)
    k_hist<<<N_GRAPH * SUBB, 256, 0, stream>>>(ei, ew, hist_c, hist_d);
    k_reduce<<<SCAN_BLOCKS, 256, 0, stream>>>(hist_c, hist_d, counts, dinv);
    k_scan1<<<SCAN_BLOCKS, 256, 0, stream>>>(counts, row_ptr, bsum);
    k_scan2<<<1, 256, 0, stream>>>(bsum);
    k_scan3<<<SCAN_BLOCKS, 256, 0, stream>>>(row_ptr, bsum);
    k_fill2<<<N_GRAPH * SUBB, 256, 0, stream>>>(ei, ew, dinv, row_ptr, hist_c, col_idx, val);
    k_wt<<<(2 * C * C) / 256, 256, 0, stream>>>(w1, w2, wt1, wt2);

    // layer 0 (collapsed: scalar agg, then expand+LN)
    k_agg0_scalar<<<NV / 256, 256, 0, stream>>>(x, row_ptr, col_idx, val, dinv, s0);
    k_l0post<<<NV, 128, 0, stream>>>(s0, w0, b0, ln_g, ln_b, bufA);

    // layer 1
    k_gemm_mfma<<<dim3(NV / 128, C / 128), 256, 0, stream>>>(bufA, wt1, bufF);
    k_agg<<<NV / 4, 256, 0, stream>>>(bufF, row_ptr, col_idx, val, dinv, b1, ln_g, ln_b, bufA);

    // layer 2
    k_gemm_mfma<<<dim3(NV / 128, C / 128), 256, 0, stream>>>(bufA, wt2, bufF);
    k_agg<<<NV / 4, 256, 0, stream>>>(bufF, row_ptr, col_idx, val, dinv, b2, ln_g, ln_b, bufA);

    // pooling + head
    k_pool1<<<dim3(N_GRAPH, POOL_CHUNKS), 256, 0, stream>>>(bufA, pmax);
    k_pool2_head<<<N_GRAPH, C, 0, stream>>>(pmax, ln_g, ln_b, head_w, head_b, out);
}

// Round 15
// 368.778 us; speedup vs baseline: 1.2274x; 1.0016x over previous
//
#include <hip/hip_runtime.h>
#include <hip/hip_bf16.h>
#include <stdint.h>

#define N_GRAPH 8
#define V_NODES 4608
#define E_PER   73728
#define NV      (N_GRAPH * V_NODES)   // 36864
#define E_TOT   (N_GRAPH * E_PER)     // 589824
#define C       512
#define NCLS    3
#define LN_EPS  1e-5f
#define POOL_CHUNKS 36                // V_NODES / 128
#define POOL_PARTS  144               // POOL_CHUNKS * 4 waves
#define SCAN_BLOCKS 144               // NV / 256
#define SUBB    32                    // sub-blocks per graph
#define EPSB    (E_PER / SUBB)        // 2304 edges per sub-block

typedef __attribute__((ext_vector_type(8))) short short8;
typedef __attribute__((ext_vector_type(4))) float floatx4;
typedef __attribute__((ext_vector_type(2))) float float2v;
typedef __attribute__((address_space(1))) void v_g;
typedef __attribute__((address_space(3))) void v_l;

// ---------------- helpers ----------------

__device__ inline float waveReduceSum(float v) {
#pragma unroll
    for (int o = 32; o > 0; o >>= 1) v += __shfl_down(v, o, 64);
    return v; // valid on lane 0
}

__device__ inline float waveAllSum(float v) {   // butterfly: all lanes get total
#pragma unroll
    for (int o = 32; o > 0; o >>= 1) v += __shfl_xor(v, o, 64);
    return v;
}

__device__ inline float blockSum512(float v, volatile float* sred) {
    float s = waveReduceSum(v);
    if ((threadIdx.x & 63) == 0) sred[threadIdx.x >> 6] = s;
    __syncthreads();
    float t = 0.f;
#pragma unroll
    for (int i = 0; i < 8; i++) t += sred[i];
    __syncthreads();
    return t;
}

__device__ inline unsigned short f2bf(float f) {   // RNE
    uint32_t u = __float_as_uint(f);
    u += 0x7fffu + ((u >> 16) & 1u);
    return (unsigned short)(u >> 16);
}
__device__ inline float bf2f(unsigned short b) {
    return __uint_as_float(((uint32_t)b) << 16);
}

// ---- fp8 e4m3fn pack/unpack (HW cvt on gfx950; guarded fallback) ----

#if __has_builtin(__builtin_amdgcn_cvt_pk_fp8_f32)
__device__ inline uint32_t pk_fp8(float a, float b) {
    return (uint32_t)__builtin_amdgcn_cvt_pk_fp8_f32(a, b, 0, false);
}
#else
__device__ inline uint32_t fp8_enc1(float f) {
    float a = fminf(fmaxf(f, -448.f), 448.f);
    uint32_t u = __float_as_uint(a);
    uint32_t s = (u >> 24) & 0x80;
    int e = (int)((u >> 23) & 0xff) - 127;
    uint32_t m = u & 0x7fffff;
    if (a == 0.f || e < -9) return s;
    if (e < -6) {                       // subnormal
        int sh = -6 - e;                // 1..3
        uint32_t full = 0x800000u | m;
        uint32_t q = full >> (20 + sh);
        uint32_t rem = full & ((1u << (20 + sh)) - 1);
        uint32_t half = 1u << (19 + sh);
        q += (rem > half || (rem == half && (q & 1)));
        return s | q;
    }
    uint32_t q = m >> 20;
    uint32_t rem = m & 0xfffff;
    q += (rem > 0x80000 || (rem == 0x80000 && (q & 1)));
    uint32_t v = ((uint32_t)(e + 7) << 3) + q;
    if (v > 0x7e) v = 0x7e;
    return s | v;
}
__device__ inline uint32_t pk_fp8(float a, float b) {
    return fp8_enc1(a) | (fp8_enc1(b) << 8);
}
#endif

#if __has_builtin(__builtin_amdgcn_cvt_pk_f32_fp8)
__device__ inline float2v up_fp8_lo(uint32_t w) { return __builtin_amdgcn_cvt_pk_f32_fp8((int)w, false); }
__device__ inline float2v up_fp8_hi(uint32_t w) { return __builtin_amdgcn_cvt_pk_f32_fp8((int)w, true); }
#else
__device__ inline float fp8_dec1(uint32_t b) {
    uint32_t s = (b >> 7) & 1u, e = (b >> 3) & 0xfu, m = b & 7u;
    float mag = e ? ldexpf(1.0f + (float)m * 0.125f, (int)e - 7)
                  : (float)m * 0.001953125f;     // m * 2^-9
    return s ? -mag : mag;
}
__device__ inline float2v up_fp8_lo(uint32_t w) {
    float2v r; r.x = fp8_dec1(w & 0xff); r.y = fp8_dec1((w >> 8) & 0xff); return r;
}
__device__ inline float2v up_fp8_hi(uint32_t w) {
    float2v r; r.x = fp8_dec1((w >> 16) & 0xff); r.y = fp8_dec1(w >> 24); return r;
}
#endif

// ------ preprocessing: per-sub-block LDS histograms, zero global atomics ---

__launch_bounds__(256)
__global__ void k_hist(const int* __restrict__ ei, const float* __restrict__ ew,
                       int* __restrict__ hist_c, float* __restrict__ hist_d) {
    __shared__ int   lcnt[V_NODES];
    __shared__ float ldeg[V_NODES];
    const int g = blockIdx.x >> 5, j = blockIdx.x & 31;
    const int tid = threadIdx.x;
    for (int i = tid; i < V_NODES; i += 256) { lcnt[i] = 0; ldeg[i] = 0.f; }
    __syncthreads();
    const int ebase = g * E_PER + j * EPSB;
    const int*   tgt = ei + E_TOT + ebase;
    const float* w   = ew + ebase;
    for (int i = tid; i < EPSB; i += 256) {
        int t = tgt[i];
        atomicAdd(&lcnt[t], 1);
        atomicAdd(&ldeg[t], w[i]);
    }
    __syncthreads();
    const size_t hb = ((size_t)g * SUBB + j) * V_NODES;
    for (int i = tid; i < V_NODES; i += 256) {
        hist_c[hb + i] = lcnt[i];
        hist_d[hb + i] = ldeg[i];
    }
}

__global__ void k_reduce(int* __restrict__ hist_c, const float* __restrict__ hist_d,
                         int* __restrict__ counts, float* __restrict__ dinv) {
    const int node = blockIdx.x * 256 + threadIdx.x;
    if (node >= NV) return;
    const int g = node / V_NODES, t = node - g * V_NODES;
    const size_t base = (size_t)g * SUBB * V_NODES + t;
    int c = 0;
    float d = 1.0f;                       // self-loop weight
#pragma unroll 8
    for (int j = 0; j < SUBB; j++) {
        const size_t idx = base + (size_t)j * V_NODES;
        int cc = hist_c[idx];
        hist_c[idx] = c;
        c += cc;
        d += hist_d[idx];
    }
    counts[node] = c;
    dinv[node] = rsqrtf(d);
}

// ---- multi-block exclusive scan of counts -> row_ptr (3 small kernels) ----

__global__ void k_scan1(const int* __restrict__ counts, int* __restrict__ row_ptr,
                        int* __restrict__ bsum) {
    __shared__ int sh[256];
    const int b = blockIdx.x, tid = threadIdx.x;
    const int idx = b * 256 + tid;
    int v = counts[idx];
    sh[tid] = v;
    __syncthreads();
#pragma unroll
    for (int off = 1; off < 256; off <<= 1) {
        int t = (tid >= off) ? sh[tid - off] : 0;
        __syncthreads();
        sh[tid] += t;
        __syncthreads();
    }
    row_ptr[idx] = sh[tid] - v;            // exclusive within block
    if (tid == 255) bsum[b] = sh[255];     // block total
}

__global__ void k_scan2(int* __restrict__ bsum) {   // 1 block, 256 threads
    __shared__ int sh[256];
    const int tid = threadIdx.x;
    int v = (tid < SCAN_BLOCKS) ? bsum[tid] : 0;
    sh[tid] = v;
    __syncthreads();
#pragma unroll
    for (int off = 1; off < 256; off <<= 1) {
        int t = (tid >= off) ? sh[tid - off] : 0;
        __syncthreads();
        sh[tid] += t;
        __syncthreads();
    }
    if (tid < SCAN_BLOCKS) bsum[tid] = sh[tid] - v;  // exclusive block offsets
}

__global__ void k_scan3(int* __restrict__ row_ptr, const int* __restrict__ bsum) {
    const int b = blockIdx.x, tid = threadIdx.x;
    const int idx = b * 256 + tid;
    row_ptr[idx] += bsum[b];
    if (idx == 0) row_ptr[NV] = E_TOT;
}

// CSR fill + layer-0 partial aggregation fused. Block (g,j) re-reads its 2304
// edges; LDS cursor = row_ptr + prefix; ALSO accumulates sacc[t] += val*x[src]
// in LDS (layer-0 D_IN=1 collapse) and dumps partials into hist_d (reused).
__launch_bounds__(256)
__global__ void k_fill2(const int* __restrict__ ei, const float* __restrict__ ew,
                        const float* __restrict__ dinv, const int* __restrict__ row_ptr,
                        const int* __restrict__ hist_c, const float* __restrict__ x,
                        int* __restrict__ col_idx, float* __restrict__ val,
                        float* __restrict__ hist_s) {
    __shared__ int   cur[V_NODES];
    __shared__ float sacc[V_NODES];
    const int g = blockIdx.x >> 5, j = blockIdx.x & 31;
    const int tid = threadIdx.x;
    const int gV = g * V_NODES;
    const size_t hb = ((size_t)g * SUBB + j) * V_NODES;
    for (int i = tid; i < V_NODES; i += 256) {
        cur[i] = row_ptr[gV + i] + hist_c[hb + i];
        sacc[i] = 0.f;
    }
    __syncthreads();
    const int ebase = g * E_PER + j * EPSB;
    const int*   src = ei + ebase;
    const int*   tgt = ei + E_TOT + ebase;
    const float* w   = ew + ebase;
    for (int i = tid; i < EPSB; i += 256) {
        int t = tgt[i];
        int s = src[i] + gV;
        float v = dinv[s] * w[i] * dinv[gV + t];
        int pos = atomicAdd(&cur[t], 1);     // LDS atomic
        col_idx[pos] = s;
        val[pos] = v;
        atomicAdd(&sacc[t], v * x[s]);       // layer-0 partial (LDS float atomic)
    }
    __syncthreads();
    for (int i = tid; i < V_NODES; i += 256)
        hist_s[hb + i] = sacc[i];
}

// ---------------- weight convert: WT[n][k] = bf16(W[k][n]) for w1,w2 ------

__global__ void k_wt(const float* __restrict__ w1, const float* __restrict__ w2,
                     unsigned short* __restrict__ wt1, unsigned short* __restrict__ wt2) {
    int idx = blockIdx.x * 256 + threadIdx.x;     // 0 .. 2*512*512-1
    int which = idx >> 18;
    int rem = idx & 0x3ffff;
    int n = rem >> 9, k = rem & 511;
    const float* W = which ? w2 : w1;
    unsigned short* WT = which ? wt2 : wt1;
    WT[n * C + k] = f2bf(W[k * C + n]);
}

// ---------------- layer 0: h0 = bf16( LN( relu(s0*w0 + b0) ) ) ------------
// s0 reconstructed from 32 per-sub-block partials (hist_s) + self term.
// One block (128 thr = 2 waves) per node.

__launch_bounds__(128)
__global__ void k_l0post(const float* __restrict__ x, const float* __restrict__ dinv,
                         const float* __restrict__ hist_s,
                         const float* __restrict__ w0, const float* __restrict__ b0,
                         const float* __restrict__ ln_g, const float* __restrict__ ln_b,
                         unsigned short* __restrict__ out) {
    const int node = blockIdx.x;
    const int tid = threadIdx.x;
    const int g = node / V_NODES, t = node - g * V_NODES;
    __shared__ float s_sh;
    if (tid < 32) {
        float p = hist_s[((size_t)g * SUBB + tid) * V_NODES + t];
#pragma unroll
        for (int o = 16; o > 0; o >>= 1) p += __shfl_xor(p, o, 32);
        if (tid == 0) {
            float dt = dinv[node];
            s_sh = dt * dt * x[node] + p;
        }
    }
    __syncthreads();
    const float s = s_sh;
    const int c4 = tid << 2;
    float4 w = *reinterpret_cast<const float4*>(&w0[c4]);
    float4 bb = *reinterpret_cast<const float4*>(&b0[c4]);
    float vx = fmaxf(s * w.x + bb.x, 0.f);
    float vy = fmaxf(s * w.y + bb.y, 0.f);
    float vz = fmaxf(s * w.z + bb.z, 0.f);
    float vw = fmaxf(s * w.w + bb.w, 0.f);
    __shared__ float redA[2], redB[2];
    float wsum = waveReduceSum(vx + vy + vz + vw);
    if ((tid & 63) == 0) redA[tid >> 6] = wsum;
    __syncthreads();
    float mu = (redA[0] + redA[1]) * (1.0f / C);
    float dx = vx - mu, dy = vy - mu, dz = vz - mu, dw = vw - mu;
    float wsq = waveReduceSum(dx * dx + dy * dy + dz * dz + dw * dw);
    if ((tid & 63) == 0) redB[tid >> 6] = wsq;
    __syncthreads();
    float rstd = rsqrtf((redB[0] + redB[1]) * (1.0f / C) + LN_EPS);
    float4 gg = *reinterpret_cast<const float4*>(&ln_g[c4]);
    float4 b = *reinterpret_cast<const float4*>(&ln_b[c4]);
    ushort4 o = { f2bf(dx * rstd * gg.x + b.x), f2bf(dy * rstd * gg.y + b.y),
                  f2bf(dz * rstd * gg.z + b.z), f2bf(dw * rstd * gg.w + b.w) };
    reinterpret_cast<ushort4*>(out)[(size_t)node * 128 + tid] = o;
}

// ---------------- bf16 MFMA GEMM: Bout(fp8) = A[M,K] @ WT[N,K]^T ----------
// 128x128 tile, 4 waves (2x2 of 64x64), 16x16x32 MFMA, BK=32.
// Epilogue packs f32 -> fp8 e4m3 (hw buffer halves the agg gather bytes).

__launch_bounds__(256)
__global__ void k_gemm_mfma(const unsigned short* __restrict__ A,
                            const unsigned short* __restrict__ WT,
                            uint8_t* __restrict__ Bout) {
    __shared__ short8 lA[512];
    __shared__ short8 lB[512];
    const int tid = threadIdx.x;
    const int lane = tid & 63;
    const int wave = tid >> 6;
    const int wr = wave >> 1, wc = wave & 1;
    const int l15 = lane & 15, kg = lane >> 4;
    const int m0 = blockIdx.x * 128;      // x = M block (288)
    const int n0 = blockIdx.y * 128;      // y = N block (4)

    floatx4 acc[4][4] = {};

    const int s0i = tid, s1i = 256 + tid;
    const int kgs0 = s0i >> 7, idx0 = s0i & 127;
    const int kgs1 = s1i >> 7, idx1 = s1i & 127;
    const unsigned short* gA0 = A + (size_t)(m0 + idx0) * C + kgs0 * 8;
    const unsigned short* gA1 = A + (size_t)(m0 + idx1) * C + kgs1 * 8;
    const unsigned short* gB0 = WT + (size_t)(n0 + idx0) * C + kgs0 * 8;
    const unsigned short* gB1 = WT + (size_t)(n0 + idx1) * C + kgs1 * 8;

    for (int k0 = 0; k0 < C; k0 += 32) {
        __builtin_amdgcn_global_load_lds((v_g*)(gA0 + k0), (v_l*)&lA[s0i], 16, 0, 0);
        __builtin_amdgcn_global_load_lds((v_g*)(gA1 + k0), (v_l*)&lA[s1i], 16, 0, 0);
        __builtin_amdgcn_global_load_lds((v_g*)(gB0 + k0), (v_l*)&lB[s0i], 16, 0, 0);
        __builtin_amdgcn_global_load_lds((v_g*)(gB1 + k0), (v_l*)&lB[s1i], 16, 0, 0);
        asm volatile("s_waitcnt vmcnt(0)" ::: "memory");
        __syncthreads();

        short8 af[4], bf[4];
#pragma unroll
        for (int mi = 0; mi < 4; mi++)
            af[mi] = lA[kg * 128 + wr * 64 + mi * 16 + l15];
#pragma unroll
        for (int ni = 0; ni < 4; ni++)
            bf[ni] = lB[kg * 128 + wc * 64 + ni * 16 + l15];
#pragma unroll
        for (int mi = 0; mi < 4; mi++)
#pragma unroll
            for (int ni = 0; ni < 4; ni++)
                acc[mi][ni] = __builtin_amdgcn_mfma_f32_16x16x32_bf16(
                    af[mi], bf[ni], acc[mi][ni], 0, 0, 0);
        __syncthreads();
    }

    // D layout: col = lane&15, row = (lane>>4)*4 + reg   [m89-verified]
#pragma unroll
    for (int mi = 0; mi < 4; mi++) {
#pragma unroll
        for (int ni = 0; ni < 4; ni++) {
            int n = n0 + wc * 64 + ni * 16 + l15;
            floatx4 v = acc[mi][ni];
            uint32_t p01 = pk_fp8(v[0], v[1]);
            uint32_t p23 = pk_fp8(v[2], v[3]);
            uint8_t* rp = Bout + (size_t)(m0 + wr * 64 + mi * 16 + kg * 4) * C + n;
            rp[0]     = (uint8_t)p01;
            rp[C]     = (uint8_t)(p01 >> 8);
            rp[2 * C] = (uint8_t)p23;
            rp[3 * C] = (uint8_t)(p23 >> 8);
        }
    }
}

// ---------------- aggregate: ONE WAVE PER NODE, fp8 gather ---------------
// 64 lanes x 8B (8 fp8) = full 512-ch row per wave. 4 nodes per 256-thr
// block; grid 9216%8==0 keeps graph g -> XCD g pinning (per-XCD set ~L2/2).

__launch_bounds__(256)
__global__ void k_agg(const uint8_t* __restrict__ hw, const int* __restrict__ row_ptr,
                      const int* __restrict__ col_idx, const float* __restrict__ val,
                      const float* __restrict__ dinv, const float* __restrict__ bias,
                      const float* __restrict__ ln_g, const float* __restrict__ ln_b,
                      unsigned short* __restrict__ out) {
    const int b = blockIdx.x;
    const int wv = threadIdx.x >> 6;
    const int lane = threadIdx.x & 63;
    const int t = (b & 7) * V_NODES + ((b >> 3) << 2) + wv;   // bijective
    const int e0 = row_ptr[t], e1 = row_ptr[t + 1];
    const uint2* hw8 = reinterpret_cast<const uint2*>(hw);    // 8 fp8 per lane

    const float dt = dinv[t];
    const float selfw = dt * dt;
    float a[8];
    {
        uint2 hv = hw8[(size_t)t * 64 + lane];
        float2v f01 = up_fp8_lo(hv.x), f23 = up_fp8_hi(hv.x);
        float2v f45 = up_fp8_lo(hv.y), f67 = up_fp8_hi(hv.y);
        a[0] = selfw * f01.x; a[1] = selfw * f01.y;
        a[2] = selfw * f23.x; a[3] = selfw * f23.y;
        a[4] = selfw * f45.x; a[5] = selfw * f45.y;
        a[6] = selfw * f67.x; a[7] = selfw * f67.y;
    }

    int e = e0;
    for (; e + 4 <= e1; e += 4) {                 // 4 gathers in flight
        int i0 = col_idx[e], i1 = col_idx[e + 1], i2 = col_idx[e + 2], i3 = col_idx[e + 3];
        float w0 = val[e], w1 = val[e + 1], w2 = val[e + 2], w3 = val[e + 3];
        uint2 h0 = hw8[(size_t)i0 * 64 + lane];
        uint2 h1 = hw8[(size_t)i1 * 64 + lane];
        uint2 h2 = hw8[(size_t)i2 * 64 + lane];
        uint2 h3 = hw8[(size_t)i3 * 64 + lane];
#define ACC8(hv, w) { \
        float2v q01 = up_fp8_lo(hv.x), q23 = up_fp8_hi(hv.x); \
        float2v q45 = up_fp8_lo(hv.y), q67 = up_fp8_hi(hv.y); \
        a[0] += (w) * q01.x; a[1] += (w) * q01.y; \
        a[2] += (w) * q23.x; a[3] += (w) * q23.y; \
        a[4] += (w) * q45.x; a[5] += (w) * q45.y; \
        a[6] += (w) * q67.x; a[7] += (w) * q67.y; }
        ACC8(h0, w0) ACC8(h1, w1) ACC8(h2, w2) ACC8(h3, w3)
    }
    for (; e < e1; e++) {
        int is = col_idx[e];
        float w = val[e];
        uint2 hv = hw8[(size_t)is * 64 + lane];
        ACC8(hv, w)
    }
#undef ACC8

    // bias + relu
    const int c8 = lane << 3;
    float4 bb0 = *reinterpret_cast<const float4*>(&bias[c8]);
    float4 bb1 = *reinterpret_cast<const float4*>(&bias[c8 + 4]);
    a[0] = fmaxf(a[0] + bb0.x, 0.f); a[1] = fmaxf(a[1] + bb0.y, 0.f);
    a[2] = fmaxf(a[2] + bb0.z, 0.f); a[3] = fmaxf(a[3] + bb0.w, 0.f);
    a[4] = fmaxf(a[4] + bb1.x, 0.f); a[5] = fmaxf(a[5] + bb1.y, 0.f);
    a[6] = fmaxf(a[6] + bb1.z, 0.f); a[7] = fmaxf(a[7] + bb1.w, 0.f);

    // layernorm, wave-local (no barriers)
    float s = a[0] + a[1] + a[2] + a[3] + a[4] + a[5] + a[6] + a[7];
    float mu = waveAllSum(s) * (1.0f / C);
    float sq = 0.f;
#pragma unroll
    for (int i = 0; i < 8; i++) { float d = a[i] - mu; sq += d * d; }
    float rstd = rsqrtf(waveAllSum(sq) * (1.0f / C) + LN_EPS);

    float4 g0 = *reinterpret_cast<const float4*>(&ln_g[c8]);
    float4 g1 = *reinterpret_cast<const float4*>(&ln_g[c8 + 4]);
    float4 z0 = *reinterpret_cast<const float4*>(&ln_b[c8]);
    float4 z1 = *reinterpret_cast<const float4*>(&ln_b[c8 + 4]);
    short8 o;
    o[0] = (short)f2bf((a[0] - mu) * rstd * g0.x + z0.x);
    o[1] = (short)f2bf((a[1] - mu) * rstd * g0.y + z0.y);
    o[2] = (short)f2bf((a[2] - mu) * rstd * g0.z + z0.z);
    o[3] = (short)f2bf((a[3] - mu) * rstd * g0.w + z0.w);
    o[4] = (short)f2bf((a[4] - mu) * rstd * g1.x + z1.x);
    o[5] = (short)f2bf((a[5] - mu) * rstd * g1.y + z1.y);
    o[6] = (short)f2bf((a[6] - mu) * rstd * g1.z + z1.z);
    o[7] = (short)f2bf((a[7] - mu) * rstd * g1.w + z1.w);
    reinterpret_cast<short8*>(out)[(size_t)t * 64 + lane] = o;
}

// ---------------- pooling + final LN + head ----------------
// pool1: 4-wave blocks, short8 row loads; one partial max per wave.

__launch_bounds__(256)
__global__ void k_pool1(const unsigned short* __restrict__ h, float* __restrict__ pmax) {
    const int g = blockIdx.x, chunk = blockIdx.y;
    const int wv = threadIdx.x >> 6, lane = threadIdx.x & 63;
    const short8* h8 = reinterpret_cast<const short8*>(h);
    const size_t r0 = (size_t)g * V_NODES + chunk * 128 + wv * 32;
    float m[8];
#pragma unroll
    for (int i = 0; i < 8; i++) m[i] = -1e30f;
    for (int r = 0; r < 32; r++) {
        short8 v = h8[(r0 + r) * 64 + lane];
#pragma unroll
        for (int i = 0; i < 8; i++) m[i] = fmaxf(m[i], bf2f((unsigned short)v[i]));
    }
    float* dst = pmax + ((size_t)(g * POOL_PARTS + chunk * 4 + wv)) * C + (lane << 3);
    float4 o0 = { m[0], m[1], m[2], m[3] };
    float4 o1 = { m[4], m[5], m[6], m[7] };
    *reinterpret_cast<float4*>(dst) = o0;
    *reinterpret_cast<float4*>(dst + 4) = o1;
}

__global__ void k_pool2_head(const float* __restrict__ pmax, const float* __restrict__ ln_g,
                             const float* __restrict__ ln_b, const float* __restrict__ hw,
                             const float* __restrict__ hb, float* __restrict__ out) {
    __shared__ float sred[8];
    int g = blockIdx.x;
    int c = threadIdx.x;  // 512
    float m = -1e30f;
    for (int j = 0; j < POOL_PARTS; j++)
        m = fmaxf(m, pmax[((size_t)g * POOL_PARTS + j) * C + c]);
    float total = blockSum512(m, sred);
    float mu = total * (1.0f / C);
    float d = m - mu;
    float var = blockSum512(d * d, sred) * (1.0f / C);
    float rstd = rsqrtf(var + LN_EPS);
    float p = d * rstd * ln_g[c] + ln_b[c];
    float r0 = blockSum512(p * hw[c * NCLS + 0], sred);
    float r1 = blockSum512(p * hw[c * NCLS + 1], sred);
    float r2 = blockSum512(p * hw[c * NCLS + 2], sred);
    if (threadIdx.x == 0) {
        out[g * NCLS + 0] = r0 + hb[0];
        out[g * NCLS + 1] = r1 + hb[1];
        out[g * NCLS + 2] = r2 + hb[2];
    }
}

// ---------------- launch ----------------

extern "C" void kernel_launch(void* const* d_in, const int* in_sizes, int n_in,
                              void* d_out, int out_size, void* d_ws, size_t ws_size,
                              hipStream_t stream) {
    const float* x      = (const float*)d_in[0];
    const float* ew     = (const float*)d_in[1];
    const float* w0     = (const float*)d_in[2];
    const float* b0     = (const float*)d_in[3];
    const float* w1     = (const float*)d_in[4];
    const float* b1     = (const float*)d_in[5];
    const float* w2     = (const float*)d_in[6];
    const float* b2     = (const float*)d_in[7];
    const float* ln_g   = (const float*)d_in[8];
    const float* ln_b   = (const float*)d_in[9];
    const float* head_w = (const float*)d_in[10];
    const float* head_b = (const float*)d_in[11];
    const int*   ei     = (const int*)d_in[12];
    float* out = (float*)d_out;

    char* p = (char*)d_ws;
    auto alloc = [&](size_t bytes) { void* r = p; p += (bytes + 255) & ~255ull; return r; };
    unsigned short* bufA = (unsigned short*)alloc((size_t)NV * C * 2);
    uint8_t*        bufF = (uint8_t*)alloc((size_t)NV * C);          // fp8 hw
    unsigned short* wt1  = (unsigned short*)alloc((size_t)C * C * 2);
    unsigned short* wt2  = (unsigned short*)alloc((size_t)C * C * 2);
    float* dinv    = (float*)alloc((size_t)NV * 4);
    int*   counts  = (int*)alloc((size_t)NV * 4);
    int*   row_ptr = (int*)alloc((size_t)(NV + 1) * 4);
    int*   bsum    = (int*)alloc((size_t)SCAN_BLOCKS * 4);
    int*   hist_c  = (int*)alloc((size_t)N_GRAPH * SUBB * V_NODES * 4);
    float* hist_d  = (float*)alloc((size_t)N_GRAPH * SUBB * V_NODES * 4);
    int*   col_idx = (int*)alloc((size_t)E_TOT * 4);
    float* val     = (float*)alloc((size_t)E_TOT * 4);
    float* pmax    = (float*)alloc((size_t)N_GRAPH * POOL_PARTS * C * 4);

    // graph preprocessing (no global atomics, full-chip parallel)
    k_hist<<<N_GRAPH * SUBB, 256, 0, stream>>>(ei, ew, hist_c, hist_d);
    k_reduce<<<SCAN_BLOCKS, 256, 0, stream>>>(hist_c, hist_d, counts, dinv);
    k_scan1<<<SCAN_BLOCKS, 256, 0, stream>>>(counts, row_ptr, bsum);
    k_scan2<<<1, 256, 0, stream>>>(bsum);
    k_scan3<<<SCAN_BLOCKS, 256, 0, stream>>>(row_ptr, bsum);
    // fill CSR + layer-0 partial agg (hist_d reused as hist_s after k_reduce)
    k_fill2<<<N_GRAPH * SUBB, 256, 0, stream>>>(ei, ew, dinv, row_ptr, hist_c, x,
                                                col_idx, val, hist_d);
    k_wt<<<(2 * C * C) / 256, 256, 0, stream>>>(w1, w2, wt1, wt2);

    // layer 0 (collapsed): reconstruct s0 from partials, expand + LN
    k_l0post<<<NV, 128, 0, stream>>>(x, dinv, hist_d, w0, b0, ln_g, ln_b, bufA);

    // layer 1
    k_gemm_mfma<<<dim3(NV / 128, C / 128), 256, 0, stream>>>(bufA, wt1, bufF);
    k_agg<<<NV / 4, 256, 0, stream>>>(bufF, row_ptr, col_idx, val, dinv, b1, ln_g, ln_b, bufA);

    // layer 2
    k_gemm_mfma<<<dim3(NV / 128, C / 128), 256, 0, stream>>>(bufA, wt2, bufF);
    k_agg<<<NV / 4, 256, 0, stream>>>(bufF, row_ptr, col_idx, val, dinv, b2, ln_g, ln_b, bufA);

    // pooling + head
    k_pool1<<<dim3(N_GRAPH, POOL_CHUNKS), 256, 0, stream>>>(bufA, pmax);
    k_pool2_head<<<N_GRAPH, C, 0, stream>>>(pmax, ln_g, ln_b, head_w, head_b, out);
}